// Round 13
// baseline (143.464 us; speedup 1.0000x reference)
//
#include <hip/hip_runtime.h>
#include <hip/hip_bf16.h>

// ---------------------------------------------------------------------------
// GANClassifier forward, round 12: launch-count reduction (17 -> 13).
//   colstats_final + foldw fused into foldbn: each block recomputes scl/shf
//   from the 64-slice PART into LDS (L2-resident, 128-256 blocks in flight),
//   then folds RPB weight rows. All stats producers normalized to 64 slices
//   (prep nf-stats and xln_stats gain in-block slice combining).
//   GEMMs / attention / logits identical to R11 (passed, 135.6 us).
// ---------------------------------------------------------------------------

#define NNODES 4096
#define CAP 128

typedef unsigned short u16;
typedef __attribute__((ext_vector_type(8))) short bf16x8;
typedef __attribute__((ext_vector_type(4))) float f32x4;

__device__ __forceinline__ float gelu_f(float x) {
    return 0.5f * x * (1.0f + erff(x * 0.70710678118654752f));
}
__device__ __forceinline__ u16 f2bf(float x) {
    union { float f; unsigned u; } v; v.f = x;
    unsigned r = v.u + 0x7fff + ((v.u >> 16) & 1);
    return (u16)(r >> 16);
}
__device__ __forceinline__ float bf2f(u16 b) {
    return __uint_as_float(((unsigned)b) << 16);
}
__device__ __forceinline__ void gload16(const void* g, void* l) {
    __builtin_amdgcn_global_load_lds(
        (const __attribute__((address_space(1))) unsigned int*)g,
        (__attribute__((address_space(3))) unsigned int*)l, 16, 0, 0);
}

// ---------------- prep: nbr lists + nf stats (64 slices) + Wp/Wl folds -----
__global__ __launch_bounds__(256) void prep_kernel(
    const unsigned char* __restrict__ adj, int* __restrict__ nbr,
    int* __restrict__ deg, const float* __restrict__ nf,
    float* __restrict__ part, u16* __restrict__ nf16,
    const float* __restrict__ Wp, const float* __restrict__ Wl,
    const float* __restrict__ cl, u16* __restrict__ Wp16,
    u16* __restrict__ WlP16, float* __restrict__ CLP)
{
    __shared__ int lists[4][CAP];
    __shared__ int cnts[4];
    __shared__ int sflag;
    __shared__ float sb[2][512];
    __shared__ float qb[2][512];
    const int t = threadIdx.x;
    const int wv = t >> 6, lane = t & 63;

    if (blockIdx.x >= NNODES + 64) {
        // ---- stats-free weight folds: Wp rows 0..255, Wl rows 256..319 ----
        const int n = blockIdx.x - (NNODES + 64);
        if (n < 256) {
            Wp16[(size_t)n * 256 + t] = f2bf(Wp[(size_t)n * 256 + t]);
        } else {
            int m = n - 256;                 // 0..63
            if (m < 40) {
                WlP16[(size_t)m * 256 + t] = f2bf(Wl[(size_t)m * 256 + t]);
                if (t == 0) CLP[m] = cl[m];
            } else {
                WlP16[(size_t)m * 256 + t] = 0;
                if (t == 0) CLP[m] = 0.f;
            }
        }
        return;
    }

    if (blockIdx.x >= NNODES) {
        // ---- nf column stats + bf16 convert; 64 blocks -> 64 slices ----
        const int bid = blockIdx.x - NNODES;          // 0..63
        const int r0 = bid * 64;
        const int cchunk = t & 127;                   // 128 float4 per row
        const int rsub = t >> 7;                      // 0,1
        float s[4] = {0.f, 0.f, 0.f, 0.f}, q[4] = {0.f, 0.f, 0.f, 0.f};
        for (int r = rsub; r < 64; r += 2) {
            float4 v = *(const float4*)(nf + (size_t)(r0 + r) * 512 + cchunk * 4);
            float vv[4] = {v.x, v.y, v.z, v.w};
            ushort4 o;
            o.x = f2bf(vv[0]); o.y = f2bf(vv[1]);
            o.z = f2bf(vv[2]); o.w = f2bf(vv[3]);
            *(ushort4*)(nf16 + (size_t)(r0 + r) * 512 + cchunk * 4) = o;
#pragma unroll
            for (int j = 0; j < 4; ++j) { s[j] += vv[j]; q[j] += vv[j] * vv[j]; }
        }
#pragma unroll
        for (int j = 0; j < 4; ++j) {
            sb[rsub][cchunk * 4 + j] = s[j];
            qb[rsub][cchunk * 4 + j] = q[j];
        }
        __syncthreads();
        if (rsub == 0) {
#pragma unroll
            for (int j = 0; j < 4; ++j) {
                int c = cchunk * 4 + j;
                part[((size_t)bid * 512 + c) * 2 + 0] = sb[0][c] + sb[1][c];
                part[((size_t)bid * 512 + c) * 2 + 1] = qb[0][c] + qb[1][c];
            }
        }
        return;
    }

    // ---- neighbor-list compaction (layout probe inlined) ----
    const int i = blockIdx.x;
    if (wv == 0) {
        bool a = adj[(size_t)lane * 4097] != 0;
        bool b = ((const unsigned int*)adj)[(size_t)lane * 4097] != 0;
        unsigned long long mA = __ballot(a);
        unsigned long long mB = __ballot(b);
        if (lane == 0) sflag = (__popcll(mA) >= __popcll(mB)) ? 0 : 1;
    }
    __syncthreads();
    int cnt = 0;
    if (sflag == 1) {
        const uint4* row = (const uint4*)((const unsigned int*)adj + (size_t)i * NNODES);
#pragma unroll
        for (int w = 0; w < 4; ++w) {
            uint4 v = row[w * 256 + t];
            unsigned wd[4] = {v.x, v.y, v.z, v.w};
#pragma unroll
            for (int j = 0; j < 4; ++j) {
                bool on = wd[j] != 0;
                unsigned long long m = __ballot(on);
                int pre = __popcll(m & ((1ull << lane) - 1ull));
                if (on && cnt + pre < CAP)
                    lists[wv][cnt + pre] = (w * 256 + t) * 4 + j;
                cnt += __popcll(m);
            }
        }
    } else {
        uint4 v = ((const uint4*)(adj + (size_t)i * NNODES))[t];
        unsigned wd[4] = {v.x, v.y, v.z, v.w};
#pragma unroll
        for (int j = 0; j < 4; ++j)
#pragma unroll
            for (int b = 0; b < 4; ++b) {
                bool on = ((wd[j] >> (8 * b)) & 0xffu) != 0;
                unsigned long long m = __ballot(on);
                int pre = __popcll(m & ((1ull << lane) - 1ull));
                if (on && cnt + pre < CAP)
                    lists[wv][cnt + pre] = t * 16 + j * 4 + b;
                cnt += __popcll(m);
            }
    }
    if (lane == 0) cnts[wv] = cnt < CAP ? cnt : CAP;
    __syncthreads();
    int offw = 0;
#pragma unroll
    for (int w2 = 0; w2 < 4; ++w2) if (w2 < wv) offw += cnts[w2];
    int myc = cnts[wv];
    for (int k = lane; k < myc; k += 64) {
        int pos = offw + k;
        if (pos < CAP) nbr[(size_t)i * CAP + pos] = lists[wv][k];
    }
    if (t == 0) {
        int tot = cnts[0] + cnts[1] + cnts[2] + cnts[3];
        deg[i] = tot < CAP ? tot : CAP;
    }
}

// ---------------- XLN column stats -> 64 slices ----------------------------
__global__ __launch_bounds__(256) void xln_stats(
    const float* __restrict__ X, float* __restrict__ part)
{
    __shared__ float sb[4][256];
    __shared__ float qb[4][256];
    const int bid = blockIdx.x;         // 64 blocks x 64 rows
    const int r0 = bid * 64;
    const int t = threadIdx.x;
    const int cchunk = t & 63;          // 64 float4 per 256-col row
    const int rsub = t >> 6;            // 0..3
    float s[4] = {0.f, 0.f, 0.f, 0.f}, q[4] = {0.f, 0.f, 0.f, 0.f};
    for (int r = rsub; r < 64; r += 4) {
        float4 v = *(const float4*)(X + (size_t)(r0 + r) * 256 + cchunk * 4);
        float vv[4] = {v.x, v.y, v.z, v.w};
#pragma unroll
        for (int j = 0; j < 4; ++j) { s[j] += vv[j]; q[j] += vv[j] * vv[j]; }
    }
#pragma unroll
    for (int j = 0; j < 4; ++j) {
        sb[rsub][cchunk * 4 + j] = s[j];
        qb[rsub][cchunk * 4 + j] = q[j];
    }
    __syncthreads();
    if (t < 64) {
#pragma unroll
        for (int j = 0; j < 4; ++j) {
            int c = t * 4 + j;
            part[((size_t)bid * 256 + c) * 2 + 0] =
                sb[0][c] + sb[1][c] + sb[2][c] + sb[3][c];
            part[((size_t)bid * 256 + c) * 2 + 1] =
                qb[0][c] + qb[1][c] + qb[2][c] + qb[3][c];
        }
    }
}

// ---------------- foldbn: BN final (from 64-slice PART) + weight fold ------
// Each block: (1) recompute scl/shf for all C columns into LDS (reads the
// L2-resident PART redundantly; 64 independent loads per column-chunk),
// (2) fold its RPB weight rows. Replaces colstats_final + foldw launches.
template<int C, int RPB>
__global__ __launch_bounds__(256) void foldbn_kernel(
    const float* __restrict__ PART, const float* __restrict__ g,
    const float* __restrict__ bt, const float* __restrict__ W,
    const float* __restrict__ bias, u16* __restrict__ W16,
    float* __restrict__ bout)
{
    constexpr int CPT = C / 256;
    __shared__ float scl_s[C];
    __shared__ float shf_s[C];
    __shared__ float redL[RPB][4];
    const int t = threadIdx.x;
    const int lane = t & 63, wv_ = t >> 6;

    // --- stats: thread owns CPT consecutive columns ---
    {
        float s[CPT], q[CPT];
#pragma unroll
        for (int j = 0; j < CPT; ++j) { s[j] = 0.f; q[j] = 0.f; }
        const int c0 = t * CPT;
        for (int b = 0; b < 64; ++b) {
            const float* p = PART + ((size_t)b * C + c0) * 2;
#pragma unroll
            for (int j = 0; j < CPT; ++j) {
                s[j] += p[j * 2 + 0];
                q[j] += p[j * 2 + 1];
            }
        }
#pragma unroll
        for (int j = 0; j < CPT; ++j) {
            int c = c0 + j;
            float m = s[j] * (1.0f / 4096.0f);
            float v = q[j] * (1.0f / 4096.0f) - m * m;
            float sc = g[c] * rsqrtf(v + 1e-5f);
            scl_s[c] = sc;
            shf_s[c] = bt[c] - m * sc;
        }
    }
    __syncthreads();

    // --- fold RPB rows ---
#pragma unroll
    for (int rr = 0; rr < RPB; ++rr) {
        int n = blockIdx.x * RPB + rr;
        const float* w = W + (size_t)n * C;
        u16* o = W16 + (size_t)n * C;
        float part = 0.f;
        for (int k = t; k < C; k += 256) {
            float wv = w[k];
            o[k] = f2bf(wv * scl_s[k]);
            part += wv * shf_s[k];
        }
#pragma unroll
        for (int off = 32; off > 0; off >>= 1) part += __shfl_down(part, off);
        if (lane == 0) redL[rr][wv_] = part;
    }
    __syncthreads();
    if (t < RPB) {
        int n = blockIdx.x * RPB + t;
        bout[n] = bias[n] + redL[t][0] + redL[t][1] + redL[t][2] + redL[t][3];
    }
}

// ---------------- 256-thr bf16 MFMA GEMM (1024-block grids) ----------------
template<bool EPI, bool S16, bool STATS>
__global__ __launch_bounds__(256) void mfma_gemm(
    const u16* __restrict__ A, const u16* __restrict__ W,
    const float* __restrict__ bias, u16* __restrict__ C16,
    float* __restrict__ PART, int M, int N, int K)
{
    __shared__ u16 As[2][4096];
    __shared__ u16 Bs[2][4096];
    __shared__ float ep1[2][64];
    __shared__ float ep2[2][64];
    const int t = threadIdx.x;
    const int lane = t & 63, wv = t >> 6;
    const int wm = (wv >> 1) * 32, wn = (wv & 1) * 32;
    const int tile_m = blockIdx.y * 64, tile_n = blockIdx.x * 64;

    f32x4 acc[2][2];
#pragma unroll
    for (int i = 0; i < 2; ++i)
#pragma unroll
        for (int j = 0; j < 2; ++j)
#pragma unroll
            for (int e = 0; e < 4; ++e) acc[i][j][e] = 0.f;

    int srow[2], soff[2];
#pragma unroll
    for (int i = 0; i < 2; ++i) {
        int f = i * 256 + t;
        srow[i] = f >> 3;
        soff[i] = ((f & 7) ^ (srow[i] & 7)) * 8;
    }
    const int wvoff = wv * 1024;
    const int frow_a0 = wm + (lane & 15);
    const int frow_b0 = wn + (lane & 15);
    const int fk = (lane >> 4) * 16;

    const int NT = K >> 6;
    int cur = 0;

#define STAGE(B, KT)                                                         \
    {                                                                        \
        _Pragma("unroll")                                                    \
        for (int i = 0; i < 2; ++i) {                                        \
            gload16(A + (size_t)(tile_m + srow[i]) * K + (KT) * 64 + soff[i],\
                    (char*)As[B] + wvoff + i * 4096);                        \
            gload16(W + (size_t)(tile_n + srow[i]) * K + (KT) * 64 + soff[i],\
                    (char*)Bs[B] + wvoff + i * 4096);                        \
        }                                                                    \
    }

    STAGE(0, 0);
    __syncthreads();
    for (int kt = 0; kt < NT; ++kt) {
        if (kt + 1 < NT) STAGE(cur ^ 1, kt + 1);
        const char* baseA = (const char*)As[cur];
        const char* baseB = (const char*)Bs[cur];
#pragma unroll
        for (int kk = 0; kk < 2; ++kk) {
            bf16x8 a[2], b[2];
#pragma unroll
            for (int mi = 0; mi < 2; ++mi) {
                int r = frow_a0 + mi * 16;
                a[mi] = *(const bf16x8*)(baseA + r * 128 +
                        ((kk * 64 + fk) ^ ((r & 7) << 4)));
            }
#pragma unroll
            for (int ni = 0; ni < 2; ++ni) {
                int r = frow_b0 + ni * 16;
                b[ni] = *(const bf16x8*)(baseB + r * 128 +
                        ((kk * 64 + fk) ^ ((r & 7) << 4)));
            }
#pragma unroll
            for (int mi = 0; mi < 2; ++mi)
#pragma unroll
                for (int ni = 0; ni < 2; ++ni)
                    acc[mi][ni] = __builtin_amdgcn_mfma_f32_16x16x32_bf16(
                        a[mi], b[ni], acc[mi][ni], 0, 0, 0);
        }
        __syncthreads();
        cur ^= 1;
    }
#undef STAGE

    float st0 = 0.f, st1 = 0.f, sq0 = 0.f, sq1 = 0.f;
#pragma unroll
    for (int mi = 0; mi < 2; ++mi) {
#pragma unroll
        for (int ni = 0; ni < 2; ++ni) {
            int col = tile_n + wn + ni * 16 + (lane & 15);
            float bs = 0.f;
            if (EPI) bs = bias[col];
#pragma unroll
            for (int e = 0; e < 4; ++e) {
                int row = tile_m + wm + mi * 16 + ((lane >> 4) << 2) + e;
                float c = acc[mi][ni][e];
                if (EPI) c = gelu_f(c + bs);
                if (S16) C16[(size_t)row * N + col] = f2bf(c);
                if (STATS) {
                    if (ni == 0) { st0 += c; sq0 += c * c; }
                    else         { st1 += c; sq1 += c * c; }
                }
            }
        }
    }

    if (STATS) {
        float s0 = st0, s1 = st1, q0 = sq0, q1 = sq1;
        s0 += __shfl_xor(s0, 16); s0 += __shfl_xor(s0, 32);
        s1 += __shfl_xor(s1, 16); s1 += __shfl_xor(s1, 32);
        q0 += __shfl_xor(q0, 16); q0 += __shfl_xor(q0, 32);
        q1 += __shfl_xor(q1, 16); q1 += __shfl_xor(q1, 32);
        if (lane < 16) {
            ep1[wv >> 1][wn + lane] = s0;       ep2[wv >> 1][wn + lane] = q0;
            ep1[wv >> 1][wn + 16 + lane] = s1;  ep2[wv >> 1][wn + 16 + lane] = q1;
        }
        __syncthreads();
        if (t < 64) {
            PART[((size_t)blockIdx.y * N + tile_n + t) * 2 + 0] = ep1[0][t] + ep1[1][t];
            PART[((size_t)blockIdx.y * N + tile_n + t) * 2 + 1] = ep2[0][t] + ep2[1][t];
        }
    }
}

// ---------------- 512-thr split-K GEMM (256-block N=256 grids) -------------
template<bool EPI, bool S16, bool ASRCF>
__global__ __launch_bounds__(512) void mfma_gemm8(
    const u16* __restrict__ A, const u16* __restrict__ W,
    const float* __restrict__ bias, u16* __restrict__ C16,
    const float* __restrict__ Wa, float* __restrict__ ASRC,
    float* __restrict__ ATGT, int M, int N, int K)
{
    __shared__ u16 As[2][2][4096];     // [dbuf][khalf][8KB]
    __shared__ u16 Bs[2][2][4096];
    __shared__ float ep1[2][64];
    __shared__ float ep2[2][64];
    const int t = threadIdx.x;
    const int lane = t & 63, wv = t >> 6;
    const int kh = wv >> 2;
    const int wl = wv & 3;
    const int wm = (wl >> 1) * 32, wn = (wl & 1) * 32;
    const int tile_m = blockIdx.y * 64, tile_n = blockIdx.x * 64;

    f32x4 acc[2][2];
#pragma unroll
    for (int i = 0; i < 2; ++i)
#pragma unroll
        for (int j = 0; j < 2; ++j)
#pragma unroll
            for (int e = 0; e < 4; ++e) acc[i][j][e] = 0.f;

    const int ht = t & 255;
    int srow[2], soff[2];
#pragma unroll
    for (int i = 0; i < 2; ++i) {
        int f = i * 256 + ht;
        srow[i] = f >> 3;
        soff[i] = ((f & 7) ^ (srow[i] & 7)) * 8;
    }
    const int wvoff = wl * 1024;
    const int frow_a0 = wm + (lane & 15);
    const int frow_b0 = wn + (lane & 15);
    const int fk = (lane >> 4) * 16;

    const int NTh = (K >> 6) >> 1;
    const int kbase = kh * NTh;
    int cur = 0;

#define STAGE8(B, KT)                                                        \
    {                                                                        \
        _Pragma("unroll")                                                    \
        for (int i = 0; i < 2; ++i) {                                        \
            gload16(A + (size_t)(tile_m + srow[i]) * K + (kbase + (KT)) * 64 \
                        + soff[i],                                           \
                    (char*)As[B][kh] + wvoff + i * 4096);                    \
            gload16(W + (size_t)(tile_n + srow[i]) * K + (kbase + (KT)) * 64 \
                        + soff[i],                                           \
                    (char*)Bs[B][kh] + wvoff + i * 4096);                    \
        }                                                                    \
    }

    STAGE8(0, 0);
    __syncthreads();
    for (int kt = 0; kt < NTh; ++kt) {
        if (kt + 1 < NTh) STAGE8(cur ^ 1, kt + 1);
        const char* baseA = (const char*)As[cur][kh];
        const char* baseB = (const char*)Bs[cur][kh];
#pragma unroll
        for (int kk = 0; kk < 2; ++kk) {
            bf16x8 a[2], b[2];
#pragma unroll
            for (int mi = 0; mi < 2; ++mi) {
                int r = frow_a0 + mi * 16;
                a[mi] = *(const bf16x8*)(baseA + r * 128 +
                        ((kk * 64 + fk) ^ ((r & 7) << 4)));
            }
#pragma unroll
            for (int ni = 0; ni < 2; ++ni) {
                int r = frow_b0 + ni * 16;
                b[ni] = *(const bf16x8*)(baseB + r * 128 +
                        ((kk * 64 + fk) ^ ((r & 7) << 4)));
            }
#pragma unroll
            for (int mi = 0; mi < 2; ++mi)
#pragma unroll
                for (int ni = 0; ni < 2; ++ni)
                    acc[mi][ni] = __builtin_amdgcn_mfma_f32_16x16x32_bf16(
                        a[mi], b[ni], acc[mi][ni], 0, 0, 0);
        }
        __syncthreads();
        cur ^= 1;
    }
#undef STAGE8

    float* cb = (float*)&As[0][0][0];
    if (kh == 1) {
#pragma unroll
        for (int mi = 0; mi < 2; ++mi)
#pragma unroll
            for (int ni = 0; ni < 2; ++ni)
#pragma unroll
                for (int e = 0; e < 4; ++e)
                    cb[wl * 1024 + lane * 16 + (mi * 2 + ni) * 4 + e] =
                        acc[mi][ni][e];
    }
    __syncthreads();
    if (kh == 0) {
#pragma unroll
        for (int mi = 0; mi < 2; ++mi)
#pragma unroll
            for (int ni = 0; ni < 2; ++ni)
#pragma unroll
                for (int e = 0; e < 4; ++e)
                    acc[mi][ni][e] +=
                        cb[wl * 1024 + lane * 16 + (mi * 2 + ni) * 4 + e];

#pragma unroll
        for (int mi = 0; mi < 2; ++mi) {
#pragma unroll
            for (int ni = 0; ni < 2; ++ni) {
                int col = tile_n + wn + ni * 16 + (lane & 15);
                float bs = 0.f;
                if (EPI) bs = bias[col];
#pragma unroll
                for (int e = 0; e < 4; ++e) {
                    int row = tile_m + wm + mi * 16 + ((lane >> 4) << 2) + e;
                    float c = acc[mi][ni][e];
                    if (EPI) c = gelu_f(c + bs);
                    if (S16) C16[(size_t)row * N + col] = f2bf(c);
                }
            }
        }
    }

    if (ASRCF) {
        if (kh == 0) {
            const int cl = lane & 15;
            float ws0 = Wa[wn + cl],      ws1 = Wa[wn + 16 + cl];
            float wt0 = Wa[64 + wn + cl], wt1 = Wa[64 + wn + 16 + cl];
#pragma unroll
            for (int mi = 0; mi < 2; ++mi)
#pragma unroll
                for (int e = 0; e < 4; ++e) {
                    float vs = acc[mi][0][e] * ws0 + acc[mi][1][e] * ws1;
                    float vt = acc[mi][0][e] * wt0 + acc[mi][1][e] * wt1;
#pragma unroll
                    for (int off = 1; off < 16; off <<= 1) {
                        vs += __shfl_xor(vs, off);
                        vt += __shfl_xor(vt, off);
                    }
                    if (cl == 0) {
                        int row = wm + mi * 16 + ((lane >> 4) << 2) + e;
                        ep1[wl & 1][row] = vs;
                        ep2[wl & 1][row] = vt;
                    }
                }
        }
        __syncthreads();
        if (t < 64) {
            int head = blockIdx.x;
            ASRC[(size_t)(tile_m + t) * 4 + head] = ep1[0][t] + ep1[1][t];
            ATGT[(size_t)(tile_m + t) * 4 + head] = ep2[0][t] + ep2[1][t];
        }
    }
}

// ---------------- gathered logits GEMM (512-thr split-K) -------------------
__global__ __launch_bounds__(512) void logits_mfma(
    const u16* __restrict__ xf16, const int* __restrict__ idxs,
    const u16* __restrict__ WlP, const float* __restrict__ clP,
    float* __restrict__ out)
{
    __shared__ u16 As[2][2][4096];
    __shared__ u16 Bs[2][2][4096];
    const int t = threadIdx.x;
    const int lane = t & 63, wv = t >> 6;
    const int kh = wv >> 2;
    const int wl = wv & 3;
    const int wm = (wl >> 1) * 32, wn = (wl & 1) * 32;
    const int tile_m = blockIdx.x * 64;

    f32x4 acc[2][2];
#pragma unroll
    for (int i = 0; i < 2; ++i)
#pragma unroll
        for (int j = 0; j < 2; ++j)
#pragma unroll
            for (int e = 0; e < 4; ++e) acc[i][j][e] = 0.f;

    const int ht = t & 255;
    int srow[2], soff[2], gr[2];
#pragma unroll
    for (int i = 0; i < 2; ++i) {
        int f = i * 256 + ht;
        srow[i] = f >> 3;
        soff[i] = ((f & 7) ^ (srow[i] & 7)) * 8;
        gr[i] = idxs[tile_m + srow[i]];
    }
    const int wvoff = wl * 1024;
    const int frow_a0 = wm + (lane & 15);
    const int frow_b0 = wn + (lane & 15);
    const int fk = (lane >> 4) * 16;
    const int kbase = kh * 2;

#define LSTAGE8(B, KT)                                                       \
    {                                                                        \
        _Pragma("unroll")                                                    \
        for (int i = 0; i < 2; ++i) {                                        \
            gload16(xf16 + (size_t)gr[i] * 256 + (kbase + (KT)) * 64         \
                        + soff[i],                                           \
                    (char*)As[B][kh] + wvoff + i * 4096);                    \
            gload16(WlP + (size_t)srow[i] * 256 + (kbase + (KT)) * 64        \
                        + soff[i],                                           \
                    (char*)Bs[B][kh] + wvoff + i * 4096);                    \
        }                                                                    \
    }

    int cur = 0;
    LSTAGE8(0, 0);
    __syncthreads();
#pragma unroll
    for (int kt = 0; kt < 2; ++kt) {
        if (kt + 1 < 2) LSTAGE8(cur ^ 1, kt + 1);
        const char* baseA = (const char*)As[cur][kh];
        const char* baseB = (const char*)Bs[cur][kh];
#pragma unroll
        for (int kk = 0; kk < 2; ++kk) {
            bf16x8 a[2], b[2];
#pragma unroll
            for (int mi = 0; mi < 2; ++mi) {
                int r = frow_a0 + mi * 16;
                a[mi] = *(const bf16x8*)(baseA + r * 128 +
                        ((kk * 64 + fk) ^ ((r & 7) << 4)));
            }
#pragma unroll
            for (int ni = 0; ni < 2; ++ni) {
                int r = frow_b0 + ni * 16;
                b[ni] = *(const bf16x8*)(baseB + r * 128 +
                        ((kk * 64 + fk) ^ ((r & 7) << 4)));
            }
#pragma unroll
            for (int mi = 0; mi < 2; ++mi)
#pragma unroll
                for (int ni = 0; ni < 2; ++ni)
                    acc[mi][ni] = __builtin_amdgcn_mfma_f32_16x16x32_bf16(
                        a[mi], b[ni], acc[mi][ni], 0, 0, 0);
        }
        __syncthreads();
        cur ^= 1;
    }
#undef LSTAGE8

    float* cb = (float*)&As[0][0][0];
    if (kh == 1) {
#pragma unroll
        for (int mi = 0; mi < 2; ++mi)
#pragma unroll
            for (int ni = 0; ni < 2; ++ni)
#pragma unroll
                for (int e = 0; e < 4; ++e)
                    cb[wl * 1024 + lane * 16 + (mi * 2 + ni) * 4 + e] =
                        acc[mi][ni][e];
    }
    __syncthreads();
    if (kh == 0) {
#pragma unroll
        for (int mi = 0; mi < 2; ++mi) {
#pragma unroll
            for (int ni = 0; ni < 2; ++ni) {
                int col = wn + ni * 16 + (lane & 15);
                if (col < 40) {
                    float bs = clP[col];
#pragma unroll
                    for (int e = 0; e < 4; ++e) {
                        int row = tile_m + wm + mi * 16 + ((lane >> 4) << 2) + e;
                        float c = acc[mi][ni][e] +
                            cb[wl * 1024 + lane * 16 + (mi * 2 + ni) * 4 + e];
                        out[(size_t)row * 40 + col] = c + bs;
                    }
                }
            }
        }
    }
}

// ---------------- attention + residual + LayerNorm (1 node/block) ----------
__global__ __launch_bounds__(256) void attn_ln_kernel(
    const u16* __restrict__ xh, const u16* __restrict__ x0,
    const float* __restrict__ asrc, const float* __restrict__ atgt,
    const int* __restrict__ nbr, const int* __restrict__ deg_,
    const float* __restrict__ ln_g, const float* __restrict__ ln_b,
    float* __restrict__ xln32, u16* __restrict__ xln16)
{
    __shared__ float att[CAP * 4];
    __shared__ int nb[CAP];
    __shared__ float red[8];
    const int i = blockIdx.x;
    const int t = threadIdx.x;
    const int wv = t >> 6, lane = t & 63;
    const int dg = deg_[i];

    for (int k = t; k < dg; k += 256) nb[k] = nbr[(size_t)i * CAP + k];
    __syncthreads();

    for (int idx = t; idx < dg * 4; idx += 256) {
        int k = idx >> 2, h = idx & 3;
        float e = asrc[nb[k] * 4 + h] + atgt[i * 4 + h];
        att[idx] = e > 0.f ? e : 0.2f * e;
    }
    __syncthreads();

    {
        const int h = wv;
        float m = -1e30f;
        for (int k = lane; k < dg; k += 64) m = fmaxf(m, att[k * 4 + h]);
#pragma unroll
        for (int off = 32; off > 0; off >>= 1) m = fmaxf(m, __shfl_xor(m, off));
        float s = 0.f;
        for (int k = lane; k < dg; k += 64) s += expf(att[k * 4 + h] - m);
#pragma unroll
        for (int off = 32; off > 0; off >>= 1) s += __shfl_xor(s, off);
        float inv = 1.0f / s;
        for (int k = lane; k < dg; k += 64)
            att[k * 4 + h] = expf(att[k * 4 + h] - m) * inv;
    }

    const int h = wv;
    float acc = 0.f;
    int k = 0;
    for (; k + 4 <= dg; k += 4) {
        float a0 = att[(k + 0) * 4 + h], v0 = bf2f(xh[(size_t)nb[k + 0] * 256 + t]);
        float a1 = att[(k + 1) * 4 + h], v1 = bf2f(xh[(size_t)nb[k + 1] * 256 + t]);
        float a2 = att[(k + 2) * 4 + h], v2 = bf2f(xh[(size_t)nb[k + 2] * 256 + t]);
        float a3 = att[(k + 3) * 4 + h], v3 = bf2f(xh[(size_t)nb[k + 3] * 256 + t]);
        acc = fmaf(a0, v0, acc); acc = fmaf(a1, v1, acc);
        acc = fmaf(a2, v2, acc); acc = fmaf(a3, v3, acc);
    }
    for (; k < dg; ++k)
        acc = fmaf(att[k * 4 + h], bf2f(xh[(size_t)nb[k] * 256 + t]), acc);

    float v = bf2f(x0[(size_t)i * 256 + t]) + acc;
    float s = v, q = v * v;
#pragma unroll
    for (int off = 32; off > 0; off >>= 1) {
        s += __shfl_xor(s, off);
        q += __shfl_xor(q, off);
    }
    if (lane == 0) { red[wv] = s; red[4 + wv] = q; }
    __syncthreads();
    float S = red[0] + red[1] + red[2] + red[3];
    float Q = red[4] + red[5] + red[6] + red[7];
    float mu = S * (1.0f / 256.0f);
    float var = Q * (1.0f / 256.0f) - mu * mu;
    float y = (v - mu) * rsqrtf(var + 1e-5f) * ln_g[t] + ln_b[t];
    xln32[(size_t)i * 256 + t] = y;
    xln16[(size_t)i * 256 + t] = f2bf(y);
}

// ---------------------------------------------------------------------------
extern "C" void kernel_launch(void* const* d_in, const int* in_sizes, int n_in,
                              void* d_out, int out_size, void* d_ws, size_t ws_size,
                              hipStream_t stream)
{
    const float* nf      = (const float*)d_in[0];
    const float* pre_g1  = (const float*)d_in[1];
    const float* pre_b1  = (const float*)d_in[2];
    const float* pre_W1  = (const float*)d_in[3];
    const float* pre_c1  = (const float*)d_in[4];
    const float* pre_g2  = (const float*)d_in[5];
    const float* pre_b2  = (const float*)d_in[6];
    const float* pre_W2  = (const float*)d_in[7];
    const float* pre_c2  = (const float*)d_in[8];
    const float* Wp      = (const float*)d_in[9];
    const float* Wa      = (const float*)d_in[10];
    const float* ln_g    = (const float*)d_in[11];
    const float* ln_b    = (const float*)d_in[12];
    const float* post_g1 = (const float*)d_in[13];
    const float* post_b1 = (const float*)d_in[14];
    const float* post_W1 = (const float*)d_in[15];
    const float* post_c1 = (const float*)d_in[16];
    const float* post_g2 = (const float*)d_in[17];
    const float* post_b2 = (const float*)d_in[18];
    const float* post_W2 = (const float*)d_in[19];
    const float* post_c2 = (const float*)d_in[20];
    const float* Wl      = (const float*)d_in[21];
    const float* cl      = (const float*)d_in[22];
    const unsigned char* adj = (const unsigned char*)d_in[23];
    const int* idxs      = (const int*)d_in[24];
    float* out = (float*)d_out;

    size_t off = 0;
    char* base = (char*)d_ws;
    auto carve = [&](size_t bytes) {
        void* p = base + off;
        off += (bytes + 255) & ~(size_t)255;
        return p;
    };
    u16*   Y16   = (u16*)  carve((size_t)4096 * 1024 * 2);
    u16*   NF16  = (u16*)  carve((size_t)4096 * 512 * 2);
    u16*   X016  = (u16*)  carve((size_t)4096 * 256 * 2);
    u16*   XH16  = (u16*)  carve((size_t)4096 * 256 * 2);
    float* XLN32 = (float*)carve((size_t)4096 * 256 * 4);
    u16*   XLN16 = (u16*)  carve((size_t)4096 * 256 * 2);
    u16*   XF16  = (u16*)  carve((size_t)4096 * 256 * 2);
    u16*   W1_16 = (u16*)  carve((size_t)1024 * 512 * 2);
    u16*   W2_16 = (u16*)  carve((size_t)256 * 1024 * 2);
    u16*   Wp16  = (u16*)  carve((size_t)256 * 256 * 2);
    u16*   W3_16 = (u16*)  carve((size_t)1024 * 256 * 2);
    u16*   W4_16 = (u16*)  carve((size_t)256 * 1024 * 2);
    u16*   WlP16 = (u16*)  carve((size_t)64 * 256 * 2);
    float* B1    = (float*)carve(1024 * 4);
    float* B2    = (float*)carve(256 * 4);
    float* B3    = (float*)carve(1024 * 4);
    float* B4    = (float*)carve(256 * 4);
    float* CLP   = (float*)carve(64 * 4);
    int*   NBR   = (int*)  carve((size_t)4096 * CAP * 4);
    int*   DEG   = (int*)  carve((size_t)4096 * 4);
    float* ASRC  = (float*)carve((size_t)4096 * 4 * 4);
    float* ATGT  = (float*)carve((size_t)4096 * 4 * 4);
    float* PART  = (float*)carve((size_t)64 * 1024 * 2 * 4);   // 512 KB
    (void)ws_size; (void)n_in; (void)in_sizes; (void)out_size;

    // 1) prep: neighbor lists + nf stats (64 slices) + Wp/Wl folds
    prep_kernel<<<NNODES + 64 + 320, 256, 0, stream>>>(
        adj, NBR, DEG, nf, PART, NF16, Wp, Wl, cl, Wp16, WlP16, CLP);

    // 2) foldbn1 (BN1 final + W1 fold) + GEMM1 -> Y16 + PART(BN2 stats)
    foldbn_kernel<512, 4><<<256, 256, 0, stream>>>(
        PART, pre_g1, pre_b1, pre_W1, pre_c1, W1_16, B1);
    mfma_gemm<true, true, true><<<dim3(16, 64), 256, 0, stream>>>(
        NF16, W1_16, B1, Y16, PART, 4096, 1024, 512);

    // 3) foldbn2 (BN2 final + W2 fold) + GEMM2 (split-K 8w) -> X016
    foldbn_kernel<1024, 2><<<128, 256, 0, stream>>>(
        PART, pre_g2, pre_b2, pre_W2, pre_c2, W2_16, B2);
    mfma_gemm8<true, true, false><<<dim3(4, 64), 512, 0, stream>>>(
        Y16, W2_16, B2, X016, nullptr, nullptr, nullptr, 4096, 256, 1024);

    // 4) GEMM3 (split-K 8w) -> XH16 + fused a_src/a_tgt
    mfma_gemm8<false, true, true><<<dim3(4, 64), 512, 0, stream>>>(
        X016, Wp16, nullptr, XH16, Wa, ASRC, ATGT, 4096, 256, 256);

    // 5) attention + residual + LN (4096 blocks)
    attn_ln_kernel<<<4096, 256, 0, stream>>>(XH16, X016, ASRC, ATGT, NBR, DEG,
                                             ln_g, ln_b, XLN32, XLN16);

    // 6) BN3 stats (64 slices) + foldbn3 + GEMM4 -> Y16 + PART(BN4 stats)
    xln_stats<<<64, 256, 0, stream>>>(XLN32, PART);
    foldbn_kernel<256, 4><<<256, 256, 0, stream>>>(
        PART, post_g1, post_b1, post_W1, post_c1, W3_16, B3);
    mfma_gemm<true, true, true><<<dim3(16, 64), 256, 0, stream>>>(
        XLN16, W3_16, B3, Y16, PART, 4096, 1024, 256);

    // 7) foldbn4 (BN4 final + W4 fold) + GEMM5 (split-K 8w) -> XF16
    foldbn_kernel<1024, 2><<<128, 256, 0, stream>>>(
        PART, post_g2, post_b2, post_W2, post_c2, W4_16, B4);
    mfma_gemm8<true, true, false><<<dim3(4, 64), 512, 0, stream>>>(
        Y16, W4_16, B4, XF16, nullptr, nullptr, nullptr, 4096, 256, 1024);

    // 8) gathered logits (split-K 8w)
    logits_mfma<<<128, 512, 0, stream>>>(XF16, idxs, WlP16, CLP, out);
}

// Round 14
// 133.997 us; speedup vs baseline: 1.0707x; 1.0707x over previous
//
#include <hip/hip_runtime.h>
#include <hip/hip_bf16.h>

// ---------------------------------------------------------------------------
// GANClassifier forward, round 13: revert R12's foldbn (regressed +8us) back
// to R11 (135.6us); restructure adjacency scan: 1024 blocks x 4 rows with
// next-row prefetch issued before current-row ballot compaction (hides the
// per-block latency wall that kept prep at ~40us across 3 implementations).
// ---------------------------------------------------------------------------

#define NNODES 4096
#define CAP 128
#define NBR_RPB 4

typedef unsigned short u16;
typedef __attribute__((ext_vector_type(8))) short bf16x8;
typedef __attribute__((ext_vector_type(4))) float f32x4;

__device__ __forceinline__ float gelu_f(float x) {
    return 0.5f * x * (1.0f + erff(x * 0.70710678118654752f));
}
__device__ __forceinline__ u16 f2bf(float x) {
    union { float f; unsigned u; } v; v.f = x;
    unsigned r = v.u + 0x7fff + ((v.u >> 16) & 1);
    return (u16)(r >> 16);
}
__device__ __forceinline__ float bf2f(u16 b) {
    return __uint_as_float(((unsigned)b) << 16);
}
__device__ __forceinline__ void gload16(const void* g, void* l) {
    __builtin_amdgcn_global_load_lds(
        (const __attribute__((address_space(1))) unsigned int*)g,
        (__attribute__((address_space(3))) unsigned int*)l, 16, 0, 0);
}

// ---------------- prep: nbr lists (4 rows/block, prefetch) + nf stats + folds
__global__ __launch_bounds__(256) void prep_kernel(
    const unsigned char* __restrict__ adj, int* __restrict__ nbr,
    int* __restrict__ deg, const float* __restrict__ nf,
    float* __restrict__ part, u16* __restrict__ nf16,
    const float* __restrict__ Wp, const float* __restrict__ Wl,
    const float* __restrict__ cl, u16* __restrict__ Wp16,
    u16* __restrict__ WlP16, float* __restrict__ CLP)
{
    __shared__ int lists[4][CAP];
    __shared__ int cnts[4];
    __shared__ int sflag;
    const int t = threadIdx.x;
    const int wv = t >> 6, lane = t & 63;

    if (blockIdx.x >= 1024 + 128) {
        // ---- stats-free weight folds: Wp rows 0..255, Wl rows 256..319 ----
        const int n = blockIdx.x - (1024 + 128);
        if (n < 256) {
            Wp16[(size_t)n * 256 + t] = f2bf(Wp[(size_t)n * 256 + t]);
        } else {
            int m = n - 256;                 // 0..63
            if (m < 40) {
                WlP16[(size_t)m * 256 + t] = f2bf(Wl[(size_t)m * 256 + t]);
                if (t == 0) CLP[m] = cl[m];
            } else {
                WlP16[(size_t)m * 256 + t] = 0;
                if (t == 0) CLP[m] = 0.f;
            }
        }
        return;
    }

    if (blockIdx.x >= 1024) {
        // ---- nf column stats + bf16 convert (float4); 128 blocks, 256 slices
        const int bid = blockIdx.x - 1024;            // 0..127
        const int r0 = bid * 32;
        const int cchunk = t & 127;                   // 128 float4 per row
        const int rsub = t >> 7;                      // 0,1
        float s[4] = {0.f, 0.f, 0.f, 0.f}, q[4] = {0.f, 0.f, 0.f, 0.f};
        for (int r = rsub; r < 32; r += 2) {
            float4 v = *(const float4*)(nf + (size_t)(r0 + r) * 512 + cchunk * 4);
            float vv[4] = {v.x, v.y, v.z, v.w};
            ushort4 o;
            o.x = f2bf(vv[0]); o.y = f2bf(vv[1]);
            o.z = f2bf(vv[2]); o.w = f2bf(vv[3]);
            *(ushort4*)(nf16 + (size_t)(r0 + r) * 512 + cchunk * 4) = o;
#pragma unroll
            for (int j = 0; j < 4; ++j) { s[j] += vv[j]; q[j] += vv[j] * vv[j]; }
        }
        const size_t slice = (size_t)bid * 2 + rsub;  // 256 slices
#pragma unroll
        for (int j = 0; j < 4; ++j) {
            int c = cchunk * 4 + j;
            part[(slice * 512 + c) * 2 + 0] = s[j];
            part[(slice * 512 + c) * 2 + 1] = q[j];
        }
        return;
    }

    // ---- neighbor lists: 4 rows per block, next-row prefetch ----
    const int i0 = blockIdx.x * NBR_RPB;
    if (wv == 0) {
        bool a = adj[(size_t)lane * 4097] != 0;
        bool b = ((const unsigned int*)adj)[(size_t)lane * 4097] != 0;
        unsigned long long mA = __ballot(a);
        unsigned long long mB = __ballot(b);
        if (lane == 0) sflag = (__popcll(mA) >= __popcll(mB)) ? 0 : 1;
    }
    __syncthreads();

    if (sflag == 1) {
        const unsigned int* adj32 = (const unsigned int*)adj;
        uint4 cur[4], nxt[4];
#pragma unroll
        for (int w = 0; w < 4; ++w)
            cur[w] = ((const uint4*)(adj32 + (size_t)i0 * NNODES))[w * 256 + t];
#pragma unroll
        for (int w = 0; w < 4; ++w) nxt[w] = cur[w];
        for (int r = 0; r < NBR_RPB; ++r) {
            const int i = i0 + r;
            if (r + 1 < NBR_RPB) {
#pragma unroll
                for (int w = 0; w < 4; ++w)
                    nxt[w] = ((const uint4*)(adj32 + (size_t)(i + 1) * NNODES))
                             [w * 256 + t];
            }
            int cnt = 0;
#pragma unroll
            for (int w = 0; w < 4; ++w) {
                unsigned wd[4] = {cur[w].x, cur[w].y, cur[w].z, cur[w].w};
#pragma unroll
                for (int j = 0; j < 4; ++j) {
                    bool on = wd[j] != 0;
                    unsigned long long m = __ballot(on);
                    int pre = __popcll(m & ((1ull << lane) - 1ull));
                    if (on && cnt + pre < CAP)
                        lists[wv][cnt + pre] = (w * 256 + t) * 4 + j;
                    cnt += __popcll(m);
                }
            }
            if (lane == 0) cnts[wv] = cnt < CAP ? cnt : CAP;
            __syncthreads();
            int offw = 0;
#pragma unroll
            for (int w2 = 0; w2 < 4; ++w2) if (w2 < wv) offw += cnts[w2];
            int myc = cnts[wv];
            for (int k = lane; k < myc; k += 64) {
                int pos = offw + k;
                if (pos < CAP) nbr[(size_t)i * CAP + pos] = lists[wv][k];
            }
            if (t == 0) {
                int tot = cnts[0] + cnts[1] + cnts[2] + cnts[3];
                deg[i] = tot < CAP ? tot : CAP;
            }
            __syncthreads();   // lists reusable for next row
#pragma unroll
            for (int w = 0; w < 4; ++w) cur[w] = nxt[w];
        }
    } else {
        uint4 cur, nxt;
        cur = ((const uint4*)(adj + (size_t)i0 * NNODES))[t];
        nxt = cur;
        for (int r = 0; r < NBR_RPB; ++r) {
            const int i = i0 + r;
            if (r + 1 < NBR_RPB)
                nxt = ((const uint4*)(adj + (size_t)(i + 1) * NNODES))[t];
            int cnt = 0;
            unsigned wd[4] = {cur.x, cur.y, cur.z, cur.w};
#pragma unroll
            for (int j = 0; j < 4; ++j)
#pragma unroll
                for (int b = 0; b < 4; ++b) {
                    bool on = ((wd[j] >> (8 * b)) & 0xffu) != 0;
                    unsigned long long m = __ballot(on);
                    int pre = __popcll(m & ((1ull << lane) - 1ull));
                    if (on && cnt + pre < CAP)
                        lists[wv][cnt + pre] = t * 16 + j * 4 + b;
                    cnt += __popcll(m);
                }
            if (lane == 0) cnts[wv] = cnt < CAP ? cnt : CAP;
            __syncthreads();
            int offw = 0;
#pragma unroll
            for (int w2 = 0; w2 < 4; ++w2) if (w2 < wv) offw += cnts[w2];
            int myc = cnts[wv];
            for (int k = lane; k < myc; k += 64) {
                int pos = offw + k;
                if (pos < CAP) nbr[(size_t)i * CAP + pos] = lists[wv][k];
            }
            if (t == 0) {
                int tot = cnts[0] + cnts[1] + cnts[2] + cnts[3];
                deg[i] = tot < CAP ? tot : CAP;
            }
            __syncthreads();
            cur = nxt;
        }
    }
}

// ---------------- XLN column stats (float4 vectorized, 512 slices) ---------
__global__ __launch_bounds__(256) void xln_stats(
    const float* __restrict__ X, float* __restrict__ part)
{
    const int bid = blockIdx.x;
    const int r0 = bid * 32;
    const int t = threadIdx.x;
    const int cchunk = t & 63;
    const int rsub = t >> 6;
    float s[4] = {0.f, 0.f, 0.f, 0.f}, q[4] = {0.f, 0.f, 0.f, 0.f};
    for (int r = rsub; r < 32; r += 4) {
        float4 v = *(const float4*)(X + (size_t)(r0 + r) * 256 + cchunk * 4);
        float vv[4] = {v.x, v.y, v.z, v.w};
#pragma unroll
        for (int j = 0; j < 4; ++j) { s[j] += vv[j]; q[j] += vv[j] * vv[j]; }
    }
    const size_t slice = (size_t)bid * 4 + rsub;
#pragma unroll
    for (int j = 0; j < 4; ++j) {
        int c = cchunk * 4 + j;
        part[(slice * 256 + c) * 2 + 0] = s[j];
        part[(slice * 256 + c) * 2 + 1] = q[j];
    }
}

// ---------------- final reduction: 16 cols x 16 slice-groups per block -----
__global__ __launch_bounds__(256) void colstats_final(
    const float* __restrict__ part, const float* __restrict__ g,
    const float* __restrict__ bt, float* __restrict__ scl,
    float* __restrict__ shf, int NB, int C)
{
    __shared__ float sred[16][17];
    __shared__ float qred[16][17];
    const int t = threadIdx.x;
    const int cs = t & 15, grp = t >> 4;
    const int c = blockIdx.x * 16 + cs;
    float s = 0.f, q = 0.f;
    for (int b = grp; b < NB; b += 16) {
        s += part[((size_t)b * C + c) * 2 + 0];
        q += part[((size_t)b * C + c) * 2 + 1];
    }
    sred[grp][cs] = s; qred[grp][cs] = q;
    __syncthreads();
    if (grp == 0) {
        float S = 0.f, Q = 0.f;
#pragma unroll
        for (int j = 0; j < 16; ++j) { S += sred[j][cs]; Q += qred[j][cs]; }
        float m = S * (1.0f / 4096.0f);
        float v = Q * (1.0f / 4096.0f) - m * m;
        float sc = g[c] * rsqrtf(v + 1e-5f);
        scl[c] = sc;
        shf[c] = bt[c] - m * sc;
    }
}

// ---------------- fold BN into weights -------------------------------------
__global__ __launch_bounds__(256) void foldw_kernel(
    const float* __restrict__ W, const float* __restrict__ scl,
    const float* __restrict__ shf, const float* __restrict__ bias,
    u16* __restrict__ W16, float* __restrict__ bout, int K, int nvalid)
{
    __shared__ float red[4];
    const int n = blockIdx.x, t = threadIdx.x;
    u16* o = W16 + (size_t)n * K;
    if (n >= nvalid) {
        for (int k = t; k < K; k += 256) o[k] = 0;
        if (t == 0) bout[n] = 0.f;
        return;
    }
    const float* w = W + (size_t)n * K;
    float part = 0.f;
    for (int k = t; k < K; k += 256) {
        float wv = w[k];
        float s = scl ? scl[k] : 1.f;
        float f = shf ? shf[k] : 0.f;
        o[k] = f2bf(wv * s);
        part += wv * f;
    }
    int lane = t & 63, wv_ = t >> 6;
#pragma unroll
    for (int off = 32; off > 0; off >>= 1) part += __shfl_down(part, off);
    if (lane == 0) red[wv_] = part;
    __syncthreads();
    if (t == 0)
        bout[n] = (bias ? bias[n] : 0.f) + red[0] + red[1] + red[2] + red[3];
}

// ---------------- 256-thr bf16 MFMA GEMM (1024-block grids) ----------------
template<bool EPI, bool S16, bool STATS>
__global__ __launch_bounds__(256) void mfma_gemm(
    const u16* __restrict__ A, const u16* __restrict__ W,
    const float* __restrict__ bias, u16* __restrict__ C16,
    float* __restrict__ PART, int M, int N, int K)
{
    __shared__ u16 As[2][4096];
    __shared__ u16 Bs[2][4096];
    __shared__ float ep1[2][64];
    __shared__ float ep2[2][64];
    const int t = threadIdx.x;
    const int lane = t & 63, wv = t >> 6;
    const int wm = (wv >> 1) * 32, wn = (wv & 1) * 32;
    const int tile_m = blockIdx.y * 64, tile_n = blockIdx.x * 64;

    f32x4 acc[2][2];
#pragma unroll
    for (int i = 0; i < 2; ++i)
#pragma unroll
        for (int j = 0; j < 2; ++j)
#pragma unroll
            for (int e = 0; e < 4; ++e) acc[i][j][e] = 0.f;

    int srow[2], soff[2];
#pragma unroll
    for (int i = 0; i < 2; ++i) {
        int f = i * 256 + t;
        srow[i] = f >> 3;
        soff[i] = ((f & 7) ^ (srow[i] & 7)) * 8;
    }
    const int wvoff = wv * 1024;
    const int frow_a0 = wm + (lane & 15);
    const int frow_b0 = wn + (lane & 15);
    const int fk = (lane >> 4) * 16;

    const int NT = K >> 6;
    int cur = 0;

#define STAGE(B, KT)                                                         \
    {                                                                        \
        _Pragma("unroll")                                                    \
        for (int i = 0; i < 2; ++i) {                                        \
            gload16(A + (size_t)(tile_m + srow[i]) * K + (KT) * 64 + soff[i],\
                    (char*)As[B] + wvoff + i * 4096);                        \
            gload16(W + (size_t)(tile_n + srow[i]) * K + (KT) * 64 + soff[i],\
                    (char*)Bs[B] + wvoff + i * 4096);                        \
        }                                                                    \
    }

    STAGE(0, 0);
    __syncthreads();
    for (int kt = 0; kt < NT; ++kt) {
        if (kt + 1 < NT) STAGE(cur ^ 1, kt + 1);
        const char* baseA = (const char*)As[cur];
        const char* baseB = (const char*)Bs[cur];
#pragma unroll
        for (int kk = 0; kk < 2; ++kk) {
            bf16x8 a[2], b[2];
#pragma unroll
            for (int mi = 0; mi < 2; ++mi) {
                int r = frow_a0 + mi * 16;
                a[mi] = *(const bf16x8*)(baseA + r * 128 +
                        ((kk * 64 + fk) ^ ((r & 7) << 4)));
            }
#pragma unroll
            for (int ni = 0; ni < 2; ++ni) {
                int r = frow_b0 + ni * 16;
                b[ni] = *(const bf16x8*)(baseB + r * 128 +
                        ((kk * 64 + fk) ^ ((r & 7) << 4)));
            }
#pragma unroll
            for (int mi = 0; mi < 2; ++mi)
#pragma unroll
                for (int ni = 0; ni < 2; ++ni)
                    acc[mi][ni] = __builtin_amdgcn_mfma_f32_16x16x32_bf16(
                        a[mi], b[ni], acc[mi][ni], 0, 0, 0);
        }
        __syncthreads();
        cur ^= 1;
    }
#undef STAGE

    float st0 = 0.f, st1 = 0.f, sq0 = 0.f, sq1 = 0.f;
#pragma unroll
    for (int mi = 0; mi < 2; ++mi) {
#pragma unroll
        for (int ni = 0; ni < 2; ++ni) {
            int col = tile_n + wn + ni * 16 + (lane & 15);
            float bs = 0.f;
            if (EPI) bs = bias[col];
#pragma unroll
            for (int e = 0; e < 4; ++e) {
                int row = tile_m + wm + mi * 16 + ((lane >> 4) << 2) + e;
                float c = acc[mi][ni][e];
                if (EPI) c = gelu_f(c + bs);
                if (S16) C16[(size_t)row * N + col] = f2bf(c);
                if (STATS) {
                    if (ni == 0) { st0 += c; sq0 += c * c; }
                    else         { st1 += c; sq1 += c * c; }
                }
            }
        }
    }

    if (STATS) {
        float s0 = st0, s1 = st1, q0 = sq0, q1 = sq1;
        s0 += __shfl_xor(s0, 16); s0 += __shfl_xor(s0, 32);
        s1 += __shfl_xor(s1, 16); s1 += __shfl_xor(s1, 32);
        q0 += __shfl_xor(q0, 16); q0 += __shfl_xor(q0, 32);
        q1 += __shfl_xor(q1, 16); q1 += __shfl_xor(q1, 32);
        if (lane < 16) {
            ep1[wv >> 1][wn + lane] = s0;       ep2[wv >> 1][wn + lane] = q0;
            ep1[wv >> 1][wn + 16 + lane] = s1;  ep2[wv >> 1][wn + 16 + lane] = q1;
        }
        __syncthreads();
        if (t < 64) {
            PART[((size_t)blockIdx.y * N + tile_n + t) * 2 + 0] = ep1[0][t] + ep1[1][t];
            PART[((size_t)blockIdx.y * N + tile_n + t) * 2 + 1] = ep2[0][t] + ep2[1][t];
        }
    }
}

// ---------------- 512-thr split-K GEMM (256-block N=256 grids) -------------
template<bool EPI, bool S16, bool ASRCF>
__global__ __launch_bounds__(512) void mfma_gemm8(
    const u16* __restrict__ A, const u16* __restrict__ W,
    const float* __restrict__ bias, u16* __restrict__ C16,
    const float* __restrict__ Wa, float* __restrict__ ASRC,
    float* __restrict__ ATGT, int M, int N, int K)
{
    __shared__ u16 As[2][2][4096];     // [dbuf][khalf][8KB]
    __shared__ u16 Bs[2][2][4096];
    __shared__ float ep1[2][64];
    __shared__ float ep2[2][64];
    const int t = threadIdx.x;
    const int lane = t & 63, wv = t >> 6;
    const int kh = wv >> 2;
    const int wl = wv & 3;
    const int wm = (wl >> 1) * 32, wn = (wl & 1) * 32;
    const int tile_m = blockIdx.y * 64, tile_n = blockIdx.x * 64;

    f32x4 acc[2][2];
#pragma unroll
    for (int i = 0; i < 2; ++i)
#pragma unroll
        for (int j = 0; j < 2; ++j)
#pragma unroll
            for (int e = 0; e < 4; ++e) acc[i][j][e] = 0.f;

    const int ht = t & 255;
    int srow[2], soff[2];
#pragma unroll
    for (int i = 0; i < 2; ++i) {
        int f = i * 256 + ht;
        srow[i] = f >> 3;
        soff[i] = ((f & 7) ^ (srow[i] & 7)) * 8;
    }
    const int wvoff = wl * 1024;
    const int frow_a0 = wm + (lane & 15);
    const int frow_b0 = wn + (lane & 15);
    const int fk = (lane >> 4) * 16;

    const int NTh = (K >> 6) >> 1;
    const int kbase = kh * NTh;
    int cur = 0;

#define STAGE8(B, KT)                                                        \
    {                                                                        \
        _Pragma("unroll")                                                    \
        for (int i = 0; i < 2; ++i) {                                        \
            gload16(A + (size_t)(tile_m + srow[i]) * K + (kbase + (KT)) * 64 \
                        + soff[i],                                           \
                    (char*)As[B][kh] + wvoff + i * 4096);                    \
            gload16(W + (size_t)(tile_n + srow[i]) * K + (kbase + (KT)) * 64 \
                        + soff[i],                                           \
                    (char*)Bs[B][kh] + wvoff + i * 4096);                    \
        }                                                                    \
    }

    STAGE8(0, 0);
    __syncthreads();
    for (int kt = 0; kt < NTh; ++kt) {
        if (kt + 1 < NTh) STAGE8(cur ^ 1, kt + 1);
        const char* baseA = (const char*)As[cur][kh];
        const char* baseB = (const char*)Bs[cur][kh];
#pragma unroll
        for (int kk = 0; kk < 2; ++kk) {
            bf16x8 a[2], b[2];
#pragma unroll
            for (int mi = 0; mi < 2; ++mi) {
                int r = frow_a0 + mi * 16;
                a[mi] = *(const bf16x8*)(baseA + r * 128 +
                        ((kk * 64 + fk) ^ ((r & 7) << 4)));
            }
#pragma unroll
            for (int ni = 0; ni < 2; ++ni) {
                int r = frow_b0 + ni * 16;
                b[ni] = *(const bf16x8*)(baseB + r * 128 +
                        ((kk * 64 + fk) ^ ((r & 7) << 4)));
            }
#pragma unroll
            for (int mi = 0; mi < 2; ++mi)
#pragma unroll
                for (int ni = 0; ni < 2; ++ni)
                    acc[mi][ni] = __builtin_amdgcn_mfma_f32_16x16x32_bf16(
                        a[mi], b[ni], acc[mi][ni], 0, 0, 0);
        }
        __syncthreads();
        cur ^= 1;
    }
#undef STAGE8

    float* cb = (float*)&As[0][0][0];
    if (kh == 1) {
#pragma unroll
        for (int mi = 0; mi < 2; ++mi)
#pragma unroll
            for (int ni = 0; ni < 2; ++ni)
#pragma unroll
                for (int e = 0; e < 4; ++e)
                    cb[wl * 1024 + lane * 16 + (mi * 2 + ni) * 4 + e] =
                        acc[mi][ni][e];
    }
    __syncthreads();
    if (kh == 0) {
#pragma unroll
        for (int mi = 0; mi < 2; ++mi)
#pragma unroll
            for (int ni = 0; ni < 2; ++ni)
#pragma unroll
                for (int e = 0; e < 4; ++e)
                    acc[mi][ni][e] +=
                        cb[wl * 1024 + lane * 16 + (mi * 2 + ni) * 4 + e];

#pragma unroll
        for (int mi = 0; mi < 2; ++mi) {
#pragma unroll
            for (int ni = 0; ni < 2; ++ni) {
                int col = tile_n + wn + ni * 16 + (lane & 15);
                float bs = 0.f;
                if (EPI) bs = bias[col];
#pragma unroll
                for (int e = 0; e < 4; ++e) {
                    int row = tile_m + wm + mi * 16 + ((lane >> 4) << 2) + e;
                    float c = acc[mi][ni][e];
                    if (EPI) c = gelu_f(c + bs);
                    if (S16) C16[(size_t)row * N + col] = f2bf(c);
                }
            }
        }
    }

    if (ASRCF) {
        if (kh == 0) {
            const int cl = lane & 15;
            float ws0 = Wa[wn + cl],      ws1 = Wa[wn + 16 + cl];
            float wt0 = Wa[64 + wn + cl], wt1 = Wa[64 + wn + 16 + cl];
#pragma unroll
            for (int mi = 0; mi < 2; ++mi)
#pragma unroll
                for (int e = 0; e < 4; ++e) {
                    float vs = acc[mi][0][e] * ws0 + acc[mi][1][e] * ws1;
                    float vt = acc[mi][0][e] * wt0 + acc[mi][1][e] * wt1;
#pragma unroll
                    for (int off = 1; off < 16; off <<= 1) {
                        vs += __shfl_xor(vs, off);
                        vt += __shfl_xor(vt, off);
                    }
                    if (cl == 0) {
                        int row = wm + mi * 16 + ((lane >> 4) << 2) + e;
                        ep1[wl & 1][row] = vs;
                        ep2[wl & 1][row] = vt;
                    }
                }
        }
        __syncthreads();
        if (t < 64) {
            int head = blockIdx.x;
            ASRC[(size_t)(tile_m + t) * 4 + head] = ep1[0][t] + ep1[1][t];
            ATGT[(size_t)(tile_m + t) * 4 + head] = ep2[0][t] + ep2[1][t];
        }
    }
}

// ---------------- gathered logits GEMM (512-thr split-K) -------------------
__global__ __launch_bounds__(512) void logits_mfma(
    const u16* __restrict__ xf16, const int* __restrict__ idxs,
    const u16* __restrict__ WlP, const float* __restrict__ clP,
    float* __restrict__ out)
{
    __shared__ u16 As[2][2][4096];
    __shared__ u16 Bs[2][2][4096];
    const int t = threadIdx.x;
    const int lane = t & 63, wv = t >> 6;
    const int kh = wv >> 2;
    const int wl = wv & 3;
    const int wm = (wl >> 1) * 32, wn = (wl & 1) * 32;
    const int tile_m = blockIdx.x * 64;

    f32x4 acc[2][2];
#pragma unroll
    for (int i = 0; i < 2; ++i)
#pragma unroll
        for (int j = 0; j < 2; ++j)
#pragma unroll
            for (int e = 0; e < 4; ++e) acc[i][j][e] = 0.f;

    const int ht = t & 255;
    int srow[2], soff[2], gr[2];
#pragma unroll
    for (int i = 0; i < 2; ++i) {
        int f = i * 256 + ht;
        srow[i] = f >> 3;
        soff[i] = ((f & 7) ^ (srow[i] & 7)) * 8;
        gr[i] = idxs[tile_m + srow[i]];
    }
    const int wvoff = wl * 1024;
    const int frow_a0 = wm + (lane & 15);
    const int frow_b0 = wn + (lane & 15);
    const int fk = (lane >> 4) * 16;
    const int kbase = kh * 2;

#define LSTAGE8(B, KT)                                                       \
    {                                                                        \
        _Pragma("unroll")                                                    \
        for (int i = 0; i < 2; ++i) {                                        \
            gload16(xf16 + (size_t)gr[i] * 256 + (kbase + (KT)) * 64         \
                        + soff[i],                                           \
                    (char*)As[B][kh] + wvoff + i * 4096);                    \
            gload16(WlP + (size_t)srow[i] * 256 + (kbase + (KT)) * 64        \
                        + soff[i],                                           \
                    (char*)Bs[B][kh] + wvoff + i * 4096);                    \
        }                                                                    \
    }

    int cur = 0;
    LSTAGE8(0, 0);
    __syncthreads();
#pragma unroll
    for (int kt = 0; kt < 2; ++kt) {
        if (kt + 1 < 2) LSTAGE8(cur ^ 1, kt + 1);
        const char* baseA = (const char*)As[cur][kh];
        const char* baseB = (const char*)Bs[cur][kh];
#pragma unroll
        for (int kk = 0; kk < 2; ++kk) {
            bf16x8 a[2], b[2];
#pragma unroll
            for (int mi = 0; mi < 2; ++mi) {
                int r = frow_a0 + mi * 16;
                a[mi] = *(const bf16x8*)(baseA + r * 128 +
                        ((kk * 64 + fk) ^ ((r & 7) << 4)));
            }
#pragma unroll
            for (int ni = 0; ni < 2; ++ni) {
                int r = frow_b0 + ni * 16;
                b[ni] = *(const bf16x8*)(baseB + r * 128 +
                        ((kk * 64 + fk) ^ ((r & 7) << 4)));
            }
#pragma unroll
            for (int mi = 0; mi < 2; ++mi)
#pragma unroll
                for (int ni = 0; ni < 2; ++ni)
                    acc[mi][ni] = __builtin_amdgcn_mfma_f32_16x16x32_bf16(
                        a[mi], b[ni], acc[mi][ni], 0, 0, 0);
        }
        __syncthreads();
        cur ^= 1;
    }
#undef LSTAGE8

    float* cb = (float*)&As[0][0][0];
    if (kh == 1) {
#pragma unroll
        for (int mi = 0; mi < 2; ++mi)
#pragma unroll
            for (int ni = 0; ni < 2; ++ni)
#pragma unroll
                for (int e = 0; e < 4; ++e)
                    cb[wl * 1024 + lane * 16 + (mi * 2 + ni) * 4 + e] =
                        acc[mi][ni][e];
    }
    __syncthreads();
    if (kh == 0) {
#pragma unroll
        for (int mi = 0; mi < 2; ++mi) {
#pragma unroll
            for (int ni = 0; ni < 2; ++ni) {
                int col = wn + ni * 16 + (lane & 15);
                if (col < 40) {
                    float bs = clP[col];
#pragma unroll
                    for (int e = 0; e < 4; ++e) {
                        int row = tile_m + wm + mi * 16 + ((lane >> 4) << 2) + e;
                        float c = acc[mi][ni][e] +
                            cb[wl * 1024 + lane * 16 + (mi * 2 + ni) * 4 + e];
                        out[(size_t)row * 40 + col] = c + bs;
                    }
                }
            }
        }
    }
}

// ---------------- attention + residual + LayerNorm (1 node/block) ----------
__global__ __launch_bounds__(256) void attn_ln_kernel(
    const u16* __restrict__ xh, const u16* __restrict__ x0,
    const float* __restrict__ asrc, const float* __restrict__ atgt,
    const int* __restrict__ nbr, const int* __restrict__ deg_,
    const float* __restrict__ ln_g, const float* __restrict__ ln_b,
    float* __restrict__ xln32, u16* __restrict__ xln16)
{
    __shared__ float att[CAP * 4];
    __shared__ int nb[CAP];
    __shared__ float red[8];
    const int i = blockIdx.x;
    const int t = threadIdx.x;
    const int wv = t >> 6, lane = t & 63;
    const int dg = deg_[i];

    for (int k = t; k < dg; k += 256) nb[k] = nbr[(size_t)i * CAP + k];
    __syncthreads();

    for (int idx = t; idx < dg * 4; idx += 256) {
        int k = idx >> 2, h = idx & 3;
        float e = asrc[nb[k] * 4 + h] + atgt[i * 4 + h];
        att[idx] = e > 0.f ? e : 0.2f * e;
    }
    __syncthreads();

    {
        const int h = wv;
        float m = -1e30f;
        for (int k = lane; k < dg; k += 64) m = fmaxf(m, att[k * 4 + h]);
#pragma unroll
        for (int off = 32; off > 0; off >>= 1) m = fmaxf(m, __shfl_xor(m, off));
        float s = 0.f;
        for (int k = lane; k < dg; k += 64) s += expf(att[k * 4 + h] - m);
#pragma unroll
        for (int off = 32; off > 0; off >>= 1) s += __shfl_xor(s, off);
        float inv = 1.0f / s;
        for (int k = lane; k < dg; k += 64)
            att[k * 4 + h] = expf(att[k * 4 + h] - m) * inv;
    }

    const int h = wv;
    float acc = 0.f;
    int k = 0;
    for (; k + 4 <= dg; k += 4) {
        float a0 = att[(k + 0) * 4 + h], v0 = bf2f(xh[(size_t)nb[k + 0] * 256 + t]);
        float a1 = att[(k + 1) * 4 + h], v1 = bf2f(xh[(size_t)nb[k + 1] * 256 + t]);
        float a2 = att[(k + 2) * 4 + h], v2 = bf2f(xh[(size_t)nb[k + 2] * 256 + t]);
        float a3 = att[(k + 3) * 4 + h], v3 = bf2f(xh[(size_t)nb[k + 3] * 256 + t]);
        acc = fmaf(a0, v0, acc); acc = fmaf(a1, v1, acc);
        acc = fmaf(a2, v2, acc); acc = fmaf(a3, v3, acc);
    }
    for (; k < dg; ++k)
        acc = fmaf(att[k * 4 + h], bf2f(xh[(size_t)nb[k] * 256 + t]), acc);

    float v = bf2f(x0[(size_t)i * 256 + t]) + acc;
    float s = v, q = v * v;
#pragma unroll
    for (int off = 32; off > 0; off >>= 1) {
        s += __shfl_xor(s, off);
        q += __shfl_xor(q, off);
    }
    if (lane == 0) { red[wv] = s; red[4 + wv] = q; }
    __syncthreads();
    float S = red[0] + red[1] + red[2] + red[3];
    float Q = red[4] + red[5] + red[6] + red[7];
    float mu = S * (1.0f / 256.0f);
    float var = Q * (1.0f / 256.0f) - mu * mu;
    float y = (v - mu) * rsqrtf(var + 1e-5f) * ln_g[t] + ln_b[t];
    xln32[(size_t)i * 256 + t] = y;
    xln16[(size_t)i * 256 + t] = f2bf(y);
}

// ---------------------------------------------------------------------------
extern "C" void kernel_launch(void* const* d_in, const int* in_sizes, int n_in,
                              void* d_out, int out_size, void* d_ws, size_t ws_size,
                              hipStream_t stream)
{
    const float* nf      = (const float*)d_in[0];
    const float* pre_g1  = (const float*)d_in[1];
    const float* pre_b1  = (const float*)d_in[2];
    const float* pre_W1  = (const float*)d_in[3];
    const float* pre_c1  = (const float*)d_in[4];
    const float* pre_g2  = (const float*)d_in[5];
    const float* pre_b2  = (const float*)d_in[6];
    const float* pre_W2  = (const float*)d_in[7];
    const float* pre_c2  = (const float*)d_in[8];
    const float* Wp      = (const float*)d_in[9];
    const float* Wa      = (const float*)d_in[10];
    const float* ln_g    = (const float*)d_in[11];
    const float* ln_b    = (const float*)d_in[12];
    const float* post_g1 = (const float*)d_in[13];
    const float* post_b1 = (const float*)d_in[14];
    const float* post_W1 = (const float*)d_in[15];
    const float* post_c1 = (const float*)d_in[16];
    const float* post_g2 = (const float*)d_in[17];
    const float* post_b2 = (const float*)d_in[18];
    const float* post_W2 = (const float*)d_in[19];
    const float* post_c2 = (const float*)d_in[20];
    const float* Wl      = (const float*)d_in[21];
    const float* cl      = (const float*)d_in[22];
    const unsigned char* adj = (const unsigned char*)d_in[23];
    const int* idxs      = (const int*)d_in[24];
    float* out = (float*)d_out;

    size_t off = 0;
    char* base = (char*)d_ws;
    auto carve = [&](size_t bytes) {
        void* p = base + off;
        off += (bytes + 255) & ~(size_t)255;
        return p;
    };
    u16*   Y16   = (u16*)  carve((size_t)4096 * 1024 * 2);
    u16*   NF16  = (u16*)  carve((size_t)4096 * 512 * 2);
    u16*   X016  = (u16*)  carve((size_t)4096 * 256 * 2);
    u16*   XH16  = (u16*)  carve((size_t)4096 * 256 * 2);
    float* XLN32 = (float*)carve((size_t)4096 * 256 * 4);
    u16*   XLN16 = (u16*)  carve((size_t)4096 * 256 * 2);
    u16*   XF16  = (u16*)  carve((size_t)4096 * 256 * 2);
    u16*   W1_16 = (u16*)  carve((size_t)1024 * 512 * 2);
    u16*   W2_16 = (u16*)  carve((size_t)256 * 1024 * 2);
    u16*   Wp16  = (u16*)  carve((size_t)256 * 256 * 2);
    u16*   W3_16 = (u16*)  carve((size_t)1024 * 256 * 2);
    u16*   W4_16 = (u16*)  carve((size_t)256 * 1024 * 2);
    u16*   WlP16 = (u16*)  carve((size_t)64 * 256 * 2);
    float* B1    = (float*)carve(1024 * 4);
    float* B2    = (float*)carve(256 * 4);
    float* B3    = (float*)carve(1024 * 4);
    float* B4    = (float*)carve(256 * 4);
    float* CLP   = (float*)carve(64 * 4);
    int*   NBR   = (int*)  carve((size_t)4096 * CAP * 4);
    int*   DEG   = (int*)  carve((size_t)4096 * 4);
    float* ASRC  = (float*)carve((size_t)4096 * 4 * 4);
    float* ATGT  = (float*)carve((size_t)4096 * 4 * 4);
    float* PART  = (float*)carve((size_t)512 * 512 * 2 * 4);
    float* SCL1  = (float*)carve(512 * 4);
    float* SHF1  = (float*)carve(512 * 4);
    float* SCL2  = (float*)carve(1024 * 4);
    float* SHF2  = (float*)carve(1024 * 4);
    float* SCL3  = (float*)carve(256 * 4);
    float* SHF3  = (float*)carve(256 * 4);
    float* SCL4  = (float*)carve(1024 * 4);
    float* SHF4  = (float*)carve(1024 * 4);
    (void)ws_size; (void)n_in; (void)in_sizes; (void)out_size;

    // 1) prep: nbr lists (1024 blocks x 4 rows) + nf stats + Wp/Wl folds
    prep_kernel<<<1024 + 128 + 320, 256, 0, stream>>>(
        adj, NBR, DEG, nf, PART, NF16, Wp, Wl, cl, Wp16, WlP16, CLP);

    // 2) stage 1: BN1 final + fold + GEMM1 -> Y16 + PART(BN2 stats)
    colstats_final<<<512 / 16, 256, 0, stream>>>(PART, pre_g1, pre_b1, SCL1, SHF1, 256, 512);
    foldw_kernel<<<1024, 256, 0, stream>>>(pre_W1, SCL1, SHF1, pre_c1, W1_16, B1, 512, 1024);
    mfma_gemm<true, true, true><<<dim3(16, 64), 256, 0, stream>>>(
        NF16, W1_16, B1, Y16, PART, 4096, 1024, 512);

    // 3) stage 2: BN2 final + fold + GEMM2 (split-K 8w) -> X016
    colstats_final<<<1024 / 16, 256, 0, stream>>>(PART, pre_g2, pre_b2, SCL2, SHF2, 64, 1024);
    foldw_kernel<<<256, 256, 0, stream>>>(pre_W2, SCL2, SHF2, pre_c2, W2_16, B2, 1024, 256);
    mfma_gemm8<true, true, false><<<dim3(4, 64), 512, 0, stream>>>(
        Y16, W2_16, B2, X016, nullptr, nullptr, nullptr, 4096, 256, 1024);

    // 4) GEMM3 (split-K 8w) -> XH16 + fused a_src/a_tgt
    mfma_gemm8<false, true, true><<<dim3(4, 64), 512, 0, stream>>>(
        X016, Wp16, nullptr, XH16, Wa, ASRC, ATGT, 4096, 256, 256);

    // 5) attention + residual + LN (4096 blocks)
    attn_ln_kernel<<<4096, 256, 0, stream>>>(XH16, X016, ASRC, ATGT, NBR, DEG,
                                             ln_g, ln_b, XLN32, XLN16);

    // 6) stage 4: BN3 stats + final + fold + GEMM4 -> Y16 + PART(BN4 stats)
    xln_stats<<<128, 256, 0, stream>>>(XLN32, PART);
    colstats_final<<<256 / 16, 256, 0, stream>>>(PART, post_g1, post_b1, SCL3, SHF3, 512, 256);
    foldw_kernel<<<1024, 256, 0, stream>>>(post_W1, SCL3, SHF3, post_c1, W3_16, B3, 256, 1024);
    mfma_gemm<true, true, true><<<dim3(16, 64), 256, 0, stream>>>(
        XLN16, W3_16, B3, Y16, PART, 4096, 1024, 256);

    // 7) stage 5: BN4 final + fold + GEMM5 (split-K 8w) -> XF16
    colstats_final<<<1024 / 16, 256, 0, stream>>>(PART, post_g2, post_b2, SCL4, SHF4, 64, 1024);
    foldw_kernel<<<256, 256, 0, stream>>>(post_W2, SCL4, SHF4, post_c2, W4_16, B4, 1024, 256);
    mfma_gemm8<true, true, false><<<dim3(4, 64), 512, 0, stream>>>(
        Y16, W4_16, B4, XF16, nullptr, nullptr, nullptr, 4096, 256, 1024);

    // 8) gathered logits (split-K 8w)
    logits_mfma<<<128, 512, 0, stream>>>(XF16, idxs, WlP16, CLP, out);
}

// Round 15
// 133.201 us; speedup vs baseline: 1.0771x; 1.0060x over previous
//
#include <hip/hip_runtime.h>
#include <hip/hip_bf16.h>

// ---------------------------------------------------------------------------
// GANClassifier forward, round 14: adjacency compaction via LDS atomics
// (kills the 16-round serial ballot chain; order is irrelevant downstream),
// 8 rows/block with next-row prefetch. All other kernels identical to R13
// (best: 134.0 us).
// ---------------------------------------------------------------------------

#define NNODES 4096
#define CAP 128
#define NBR_RPB 8

typedef unsigned short u16;
typedef __attribute__((ext_vector_type(8))) short bf16x8;
typedef __attribute__((ext_vector_type(4))) float f32x4;

__device__ __forceinline__ float gelu_f(float x) {
    return 0.5f * x * (1.0f + erff(x * 0.70710678118654752f));
}
__device__ __forceinline__ u16 f2bf(float x) {
    union { float f; unsigned u; } v; v.f = x;
    unsigned r = v.u + 0x7fff + ((v.u >> 16) & 1);
    return (u16)(r >> 16);
}
__device__ __forceinline__ float bf2f(u16 b) {
    return __uint_as_float(((unsigned)b) << 16);
}
__device__ __forceinline__ void gload16(const void* g, void* l) {
    __builtin_amdgcn_global_load_lds(
        (const __attribute__((address_space(1))) unsigned int*)g,
        (__attribute__((address_space(3))) unsigned int*)l, 16, 0, 0);
}

// ---------------- prep: nbr lists (8 rows/block, atomic compaction) --------
__global__ __launch_bounds__(256) void prep_kernel(
    const unsigned char* __restrict__ adj, int* __restrict__ nbr,
    int* __restrict__ deg, const float* __restrict__ nf,
    float* __restrict__ part, u16* __restrict__ nf16,
    const float* __restrict__ Wp, const float* __restrict__ Wl,
    const float* __restrict__ cl, u16* __restrict__ Wp16,
    u16* __restrict__ WlP16, float* __restrict__ CLP)
{
    __shared__ int lst[CAP];
    __shared__ int cntbuf[2];
    __shared__ int sflag;
    const int t = threadIdx.x;
    const int wv = t >> 6, lane = t & 63;

    if (blockIdx.x >= 512 + 128) {
        // ---- stats-free weight folds: Wp rows 0..255, Wl rows 256..319 ----
        const int n = blockIdx.x - (512 + 128);
        if (n < 256) {
            Wp16[(size_t)n * 256 + t] = f2bf(Wp[(size_t)n * 256 + t]);
        } else {
            int m = n - 256;                 // 0..63
            if (m < 40) {
                WlP16[(size_t)m * 256 + t] = f2bf(Wl[(size_t)m * 256 + t]);
                if (t == 0) CLP[m] = cl[m];
            } else {
                WlP16[(size_t)m * 256 + t] = 0;
                if (t == 0) CLP[m] = 0.f;
            }
        }
        return;
    }

    if (blockIdx.x >= 512) {
        // ---- nf column stats + bf16 convert (float4); 128 blocks, 256 slices
        const int bid = blockIdx.x - 512;             // 0..127
        const int r0 = bid * 32;
        const int cchunk = t & 127;                   // 128 float4 per row
        const int rsub = t >> 7;                      // 0,1
        float s[4] = {0.f, 0.f, 0.f, 0.f}, q[4] = {0.f, 0.f, 0.f, 0.f};
        for (int r = rsub; r < 32; r += 2) {
            float4 v = *(const float4*)(nf + (size_t)(r0 + r) * 512 + cchunk * 4);
            float vv[4] = {v.x, v.y, v.z, v.w};
            ushort4 o;
            o.x = f2bf(vv[0]); o.y = f2bf(vv[1]);
            o.z = f2bf(vv[2]); o.w = f2bf(vv[3]);
            *(ushort4*)(nf16 + (size_t)(r0 + r) * 512 + cchunk * 4) = o;
#pragma unroll
            for (int j = 0; j < 4; ++j) { s[j] += vv[j]; q[j] += vv[j] * vv[j]; }
        }
        const size_t slice = (size_t)bid * 2 + rsub;  // 256 slices
#pragma unroll
        for (int j = 0; j < 4; ++j) {
            int c = cchunk * 4 + j;
            part[(slice * 512 + c) * 2 + 0] = s[j];
            part[(slice * 512 + c) * 2 + 1] = q[j];
        }
        return;
    }

    // ---- neighbor lists: 8 rows/block, LDS-atomic compaction --------------
    const int i0 = blockIdx.x * NBR_RPB;
    if (wv == 0) {
        bool a = adj[(size_t)lane * 4097] != 0;
        bool b = ((const unsigned int*)adj)[(size_t)lane * 4097] != 0;
        unsigned long long mA = __ballot(a);
        unsigned long long mB = __ballot(b);
        if (lane == 0) sflag = (__popcll(mA) >= __popcll(mB)) ? 0 : 1;
    }
    if (t == 0) { cntbuf[0] = 0; cntbuf[1] = 0; }
    __syncthreads();

    if (sflag == 1) {
        // 4-byte layout: 1024 uint4 per row; thread owns 4 (16 words)
        const uint4* base4 = (const uint4*)adj;
        uint4 cur[4], nxt[4];
#pragma unroll
        for (int w = 0; w < 4; ++w)
            cur[w] = base4[(size_t)i0 * 1024 + w * 256 + t];
        for (int r = 0; r < NBR_RPB; ++r) {
            const int i = i0 + r;
            if (r + 1 < NBR_RPB) {
#pragma unroll
                for (int w = 0; w < 4; ++w)
                    nxt[w] = base4[(size_t)(i + 1) * 1024 + w * 256 + t];
            }
            int* pc = &cntbuf[r & 1];
#pragma unroll
            for (int w = 0; w < 4; ++w) {
                unsigned any = cur[w].x | cur[w].y | cur[w].z | cur[w].w;
                if (any) {   // fast-path skip (~87% of thread-quads all-zero)
                    unsigned wd[4] = {cur[w].x, cur[w].y, cur[w].z, cur[w].w};
#pragma unroll
                    for (int j = 0; j < 4; ++j) {
                        if (wd[j]) {
                            int pos = atomicAdd(pc, 1);
                            if (pos < CAP)
                                lst[pos] = (w * 256 + t) * 4 + j;
                        }
                    }
                }
            }
            __syncthreads();
            int c = cntbuf[r & 1];
            if (c > CAP) c = CAP;
            for (int k = t; k < c; k += 256) nbr[(size_t)i * CAP + k] = lst[k];
            if (t == 0) {
                deg[i] = c;
                cntbuf[(r + 1) & 1] = 0;   // slot for row r+1 (safe: see R14 notes)
            }
            __syncthreads();
#pragma unroll
            for (int w = 0; w < 4; ++w) cur[w] = nxt[w];
        }
    } else {
        // u8 layout: 256 uint4 per row; thread owns 1 (16 bytes)
        uint4 cur, nxt;
        cur = ((const uint4*)(adj + (size_t)i0 * NNODES))[t];
        for (int r = 0; r < NBR_RPB; ++r) {
            const int i = i0 + r;
            if (r + 1 < NBR_RPB)
                nxt = ((const uint4*)(adj + (size_t)(i + 1) * NNODES))[t];
            int* pc = &cntbuf[r & 1];
            unsigned wd[4] = {cur.x, cur.y, cur.z, cur.w};
            unsigned any = wd[0] | wd[1] | wd[2] | wd[3];
            if (any) {
#pragma unroll
                for (int j = 0; j < 4; ++j) {
                    unsigned v = wd[j];
                    if (v) {
#pragma unroll
                        for (int b = 0; b < 4; ++b) {
                            if ((v >> (8 * b)) & 0xffu) {
                                int pos = atomicAdd(pc, 1);
                                if (pos < CAP)
                                    lst[pos] = t * 16 + j * 4 + b;
                            }
                        }
                    }
                }
            }
            __syncthreads();
            int c = cntbuf[r & 1];
            if (c > CAP) c = CAP;
            for (int k = t; k < c; k += 256) nbr[(size_t)i * CAP + k] = lst[k];
            if (t == 0) {
                deg[i] = c;
                cntbuf[(r + 1) & 1] = 0;
            }
            __syncthreads();
            cur = nxt;
        }
    }
}

// ---------------- XLN column stats (float4 vectorized, 512 slices) ---------
__global__ __launch_bounds__(256) void xln_stats(
    const float* __restrict__ X, float* __restrict__ part)
{
    const int bid = blockIdx.x;
    const int r0 = bid * 32;
    const int t = threadIdx.x;
    const int cchunk = t & 63;
    const int rsub = t >> 6;
    float s[4] = {0.f, 0.f, 0.f, 0.f}, q[4] = {0.f, 0.f, 0.f, 0.f};
    for (int r = rsub; r < 32; r += 4) {
        float4 v = *(const float4*)(X + (size_t)(r0 + r) * 256 + cchunk * 4);
        float vv[4] = {v.x, v.y, v.z, v.w};
#pragma unroll
        for (int j = 0; j < 4; ++j) { s[j] += vv[j]; q[j] += vv[j] * vv[j]; }
    }
    const size_t slice = (size_t)bid * 4 + rsub;
#pragma unroll
    for (int j = 0; j < 4; ++j) {
        int c = cchunk * 4 + j;
        part[(slice * 256 + c) * 2 + 0] = s[j];
        part[(slice * 256 + c) * 2 + 1] = q[j];
    }
}

// ---------------- final reduction: 16 cols x 16 slice-groups per block -----
__global__ __launch_bounds__(256) void colstats_final(
    const float* __restrict__ part, const float* __restrict__ g,
    const float* __restrict__ bt, float* __restrict__ scl,
    float* __restrict__ shf, int NB, int C)
{
    __shared__ float sred[16][17];
    __shared__ float qred[16][17];
    const int t = threadIdx.x;
    const int cs = t & 15, grp = t >> 4;
    const int c = blockIdx.x * 16 + cs;
    float s = 0.f, q = 0.f;
    for (int b = grp; b < NB; b += 16) {
        s += part[((size_t)b * C + c) * 2 + 0];
        q += part[((size_t)b * C + c) * 2 + 1];
    }
    sred[grp][cs] = s; qred[grp][cs] = q;
    __syncthreads();
    if (grp == 0) {
        float S = 0.f, Q = 0.f;
#pragma unroll
        for (int j = 0; j < 16; ++j) { S += sred[j][cs]; Q += qred[j][cs]; }
        float m = S * (1.0f / 4096.0f);
        float v = Q * (1.0f / 4096.0f) - m * m;
        float sc = g[c] * rsqrtf(v + 1e-5f);
        scl[c] = sc;
        shf[c] = bt[c] - m * sc;
    }
}

// ---------------- fold BN into weights -------------------------------------
__global__ __launch_bounds__(256) void foldw_kernel(
    const float* __restrict__ W, const float* __restrict__ scl,
    const float* __restrict__ shf, const float* __restrict__ bias,
    u16* __restrict__ W16, float* __restrict__ bout, int K, int nvalid)
{
    __shared__ float red[4];
    const int n = blockIdx.x, t = threadIdx.x;
    u16* o = W16 + (size_t)n * K;
    if (n >= nvalid) {
        for (int k = t; k < K; k += 256) o[k] = 0;
        if (t == 0) bout[n] = 0.f;
        return;
    }
    const float* w = W + (size_t)n * K;
    float part = 0.f;
    for (int k = t; k < K; k += 256) {
        float wv = w[k];
        float s = scl ? scl[k] : 1.f;
        float f = shf ? shf[k] : 0.f;
        o[k] = f2bf(wv * s);
        part += wv * f;
    }
    int lane = t & 63, wv_ = t >> 6;
#pragma unroll
    for (int off = 32; off > 0; off >>= 1) part += __shfl_down(part, off);
    if (lane == 0) red[wv_] = part;
    __syncthreads();
    if (t == 0)
        bout[n] = (bias ? bias[n] : 0.f) + red[0] + red[1] + red[2] + red[3];
}

// ---------------- 256-thr bf16 MFMA GEMM (1024-block grids) ----------------
template<bool EPI, bool S16, bool STATS>
__global__ __launch_bounds__(256) void mfma_gemm(
    const u16* __restrict__ A, const u16* __restrict__ W,
    const float* __restrict__ bias, u16* __restrict__ C16,
    float* __restrict__ PART, int M, int N, int K)
{
    __shared__ u16 As[2][4096];
    __shared__ u16 Bs[2][4096];
    __shared__ float ep1[2][64];
    __shared__ float ep2[2][64];
    const int t = threadIdx.x;
    const int lane = t & 63, wv = t >> 6;
    const int wm = (wv >> 1) * 32, wn = (wv & 1) * 32;
    const int tile_m = blockIdx.y * 64, tile_n = blockIdx.x * 64;

    f32x4 acc[2][2];
#pragma unroll
    for (int i = 0; i < 2; ++i)
#pragma unroll
        for (int j = 0; j < 2; ++j)
#pragma unroll
            for (int e = 0; e < 4; ++e) acc[i][j][e] = 0.f;

    int srow[2], soff[2];
#pragma unroll
    for (int i = 0; i < 2; ++i) {
        int f = i * 256 + t;
        srow[i] = f >> 3;
        soff[i] = ((f & 7) ^ (srow[i] & 7)) * 8;
    }
    const int wvoff = wv * 1024;
    const int frow_a0 = wm + (lane & 15);
    const int frow_b0 = wn + (lane & 15);
    const int fk = (lane >> 4) * 16;

    const int NT = K >> 6;
    int cur = 0;

#define STAGE(B, KT)                                                         \
    {                                                                        \
        _Pragma("unroll")                                                    \
        for (int i = 0; i < 2; ++i) {                                        \
            gload16(A + (size_t)(tile_m + srow[i]) * K + (KT) * 64 + soff[i],\
                    (char*)As[B] + wvoff + i * 4096);                        \
            gload16(W + (size_t)(tile_n + srow[i]) * K + (KT) * 64 + soff[i],\
                    (char*)Bs[B] + wvoff + i * 4096);                        \
        }                                                                    \
    }

    STAGE(0, 0);
    __syncthreads();
    for (int kt = 0; kt < NT; ++kt) {
        if (kt + 1 < NT) STAGE(cur ^ 1, kt + 1);
        const char* baseA = (const char*)As[cur];
        const char* baseB = (const char*)Bs[cur];
#pragma unroll
        for (int kk = 0; kk < 2; ++kk) {
            bf16x8 a[2], b[2];
#pragma unroll
            for (int mi = 0; mi < 2; ++mi) {
                int r = frow_a0 + mi * 16;
                a[mi] = *(const bf16x8*)(baseA + r * 128 +
                        ((kk * 64 + fk) ^ ((r & 7) << 4)));
            }
#pragma unroll
            for (int ni = 0; ni < 2; ++ni) {
                int r = frow_b0 + ni * 16;
                b[ni] = *(const bf16x8*)(baseB + r * 128 +
                        ((kk * 64 + fk) ^ ((r & 7) << 4)));
            }
#pragma unroll
            for (int mi = 0; mi < 2; ++mi)
#pragma unroll
                for (int ni = 0; ni < 2; ++ni)
                    acc[mi][ni] = __builtin_amdgcn_mfma_f32_16x16x32_bf16(
                        a[mi], b[ni], acc[mi][ni], 0, 0, 0);
        }
        __syncthreads();
        cur ^= 1;
    }
#undef STAGE

    float st0 = 0.f, st1 = 0.f, sq0 = 0.f, sq1 = 0.f;
#pragma unroll
    for (int mi = 0; mi < 2; ++mi) {
#pragma unroll
        for (int ni = 0; ni < 2; ++ni) {
            int col = tile_n + wn + ni * 16 + (lane & 15);
            float bs = 0.f;
            if (EPI) bs = bias[col];
#pragma unroll
            for (int e = 0; e < 4; ++e) {
                int row = tile_m + wm + mi * 16 + ((lane >> 4) << 2) + e;
                float c = acc[mi][ni][e];
                if (EPI) c = gelu_f(c + bs);
                if (S16) C16[(size_t)row * N + col] = f2bf(c);
                if (STATS) {
                    if (ni == 0) { st0 += c; sq0 += c * c; }
                    else         { st1 += c; sq1 += c * c; }
                }
            }
        }
    }

    if (STATS) {
        float s0 = st0, s1 = st1, q0 = sq0, q1 = sq1;
        s0 += __shfl_xor(s0, 16); s0 += __shfl_xor(s0, 32);
        s1 += __shfl_xor(s1, 16); s1 += __shfl_xor(s1, 32);
        q0 += __shfl_xor(q0, 16); q0 += __shfl_xor(q0, 32);
        q1 += __shfl_xor(q1, 16); q1 += __shfl_xor(q1, 32);
        if (lane < 16) {
            ep1[wv >> 1][wn + lane] = s0;       ep2[wv >> 1][wn + lane] = q0;
            ep1[wv >> 1][wn + 16 + lane] = s1;  ep2[wv >> 1][wn + 16 + lane] = q1;
        }
        __syncthreads();
        if (t < 64) {
            PART[((size_t)blockIdx.y * N + tile_n + t) * 2 + 0] = ep1[0][t] + ep1[1][t];
            PART[((size_t)blockIdx.y * N + tile_n + t) * 2 + 1] = ep2[0][t] + ep2[1][t];
        }
    }
}

// ---------------- 512-thr split-K GEMM (256-block N=256 grids) -------------
template<bool EPI, bool S16, bool ASRCF>
__global__ __launch_bounds__(512) void mfma_gemm8(
    const u16* __restrict__ A, const u16* __restrict__ W,
    const float* __restrict__ bias, u16* __restrict__ C16,
    const float* __restrict__ Wa, float* __restrict__ ASRC,
    float* __restrict__ ATGT, int M, int N, int K)
{
    __shared__ u16 As[2][2][4096];     // [dbuf][khalf][8KB]
    __shared__ u16 Bs[2][2][4096];
    __shared__ float ep1[2][64];
    __shared__ float ep2[2][64];
    const int t = threadIdx.x;
    const int lane = t & 63, wv = t >> 6;
    const int kh = wv >> 2;
    const int wl = wv & 3;
    const int wm = (wl >> 1) * 32, wn = (wl & 1) * 32;
    const int tile_m = blockIdx.y * 64, tile_n = blockIdx.x * 64;

    f32x4 acc[2][2];
#pragma unroll
    for (int i = 0; i < 2; ++i)
#pragma unroll
        for (int j = 0; j < 2; ++j)
#pragma unroll
            for (int e = 0; e < 4; ++e) acc[i][j][e] = 0.f;

    const int ht = t & 255;
    int srow[2], soff[2];
#pragma unroll
    for (int i = 0; i < 2; ++i) {
        int f = i * 256 + ht;
        srow[i] = f >> 3;
        soff[i] = ((f & 7) ^ (srow[i] & 7)) * 8;
    }
    const int wvoff = wl * 1024;
    const int frow_a0 = wm + (lane & 15);
    const int frow_b0 = wn + (lane & 15);
    const int fk = (lane >> 4) * 16;

    const int NTh = (K >> 6) >> 1;
    const int kbase = kh * NTh;
    int cur = 0;

#define STAGE8(B, KT)                                                        \
    {                                                                        \
        _Pragma("unroll")                                                    \
        for (int i = 0; i < 2; ++i) {                                        \
            gload16(A + (size_t)(tile_m + srow[i]) * K + (kbase + (KT)) * 64 \
                        + soff[i],                                           \
                    (char*)As[B][kh] + wvoff + i * 4096);                    \
            gload16(W + (size_t)(tile_n + srow[i]) * K + (kbase + (KT)) * 64 \
                        + soff[i],                                           \
                    (char*)Bs[B][kh] + wvoff + i * 4096);                    \
        }                                                                    \
    }

    STAGE8(0, 0);
    __syncthreads();
    for (int kt = 0; kt < NTh; ++kt) {
        if (kt + 1 < NTh) STAGE8(cur ^ 1, kt + 1);
        const char* baseA = (const char*)As[cur][kh];
        const char* baseB = (const char*)Bs[cur][kh];
#pragma unroll
        for (int kk = 0; kk < 2; ++kk) {
            bf16x8 a[2], b[2];
#pragma unroll
            for (int mi = 0; mi < 2; ++mi) {
                int r = frow_a0 + mi * 16;
                a[mi] = *(const bf16x8*)(baseA + r * 128 +
                        ((kk * 64 + fk) ^ ((r & 7) << 4)));
            }
#pragma unroll
            for (int ni = 0; ni < 2; ++ni) {
                int r = frow_b0 + ni * 16;
                b[ni] = *(const bf16x8*)(baseB + r * 128 +
                        ((kk * 64 + fk) ^ ((r & 7) << 4)));
            }
#pragma unroll
            for (int mi = 0; mi < 2; ++mi)
#pragma unroll
                for (int ni = 0; ni < 2; ++ni)
                    acc[mi][ni] = __builtin_amdgcn_mfma_f32_16x16x32_bf16(
                        a[mi], b[ni], acc[mi][ni], 0, 0, 0);
        }
        __syncthreads();
        cur ^= 1;
    }
#undef STAGE8

    float* cb = (float*)&As[0][0][0];
    if (kh == 1) {
#pragma unroll
        for (int mi = 0; mi < 2; ++mi)
#pragma unroll
            for (int ni = 0; ni < 2; ++ni)
#pragma unroll
                for (int e = 0; e < 4; ++e)
                    cb[wl * 1024 + lane * 16 + (mi * 2 + ni) * 4 + e] =
                        acc[mi][ni][e];
    }
    __syncthreads();
    if (kh == 0) {
#pragma unroll
        for (int mi = 0; mi < 2; ++mi)
#pragma unroll
            for (int ni = 0; ni < 2; ++ni)
#pragma unroll
                for (int e = 0; e < 4; ++e)
                    acc[mi][ni][e] +=
                        cb[wl * 1024 + lane * 16 + (mi * 2 + ni) * 4 + e];

#pragma unroll
        for (int mi = 0; mi < 2; ++mi) {
#pragma unroll
            for (int ni = 0; ni < 2; ++ni) {
                int col = tile_n + wn + ni * 16 + (lane & 15);
                float bs = 0.f;
                if (EPI) bs = bias[col];
#pragma unroll
                for (int e = 0; e < 4; ++e) {
                    int row = tile_m + wm + mi * 16 + ((lane >> 4) << 2) + e;
                    float c = acc[mi][ni][e];
                    if (EPI) c = gelu_f(c + bs);
                    if (S16) C16[(size_t)row * N + col] = f2bf(c);
                }
            }
        }
    }

    if (ASRCF) {
        if (kh == 0) {
            const int cl = lane & 15;
            float ws0 = Wa[wn + cl],      ws1 = Wa[wn + 16 + cl];
            float wt0 = Wa[64 + wn + cl], wt1 = Wa[64 + wn + 16 + cl];
#pragma unroll
            for (int mi = 0; mi < 2; ++mi)
#pragma unroll
                for (int e = 0; e < 4; ++e) {
                    float vs = acc[mi][0][e] * ws0 + acc[mi][1][e] * ws1;
                    float vt = acc[mi][0][e] * wt0 + acc[mi][1][e] * wt1;
#pragma unroll
                    for (int off = 1; off < 16; off <<= 1) {
                        vs += __shfl_xor(vs, off);
                        vt += __shfl_xor(vt, off);
                    }
                    if (cl == 0) {
                        int row = wm + mi * 16 + ((lane >> 4) << 2) + e;
                        ep1[wl & 1][row] = vs;
                        ep2[wl & 1][row] = vt;
                    }
                }
        }
        __syncthreads();
        if (t < 64) {
            int head = blockIdx.x;
            ASRC[(size_t)(tile_m + t) * 4 + head] = ep1[0][t] + ep1[1][t];
            ATGT[(size_t)(tile_m + t) * 4 + head] = ep2[0][t] + ep2[1][t];
        }
    }
}

// ---------------- gathered logits GEMM (512-thr split-K) -------------------
__global__ __launch_bounds__(512) void logits_mfma(
    const u16* __restrict__ xf16, const int* __restrict__ idxs,
    const u16* __restrict__ WlP, const float* __restrict__ clP,
    float* __restrict__ out)
{
    __shared__ u16 As[2][2][4096];
    __shared__ u16 Bs[2][2][4096];
    const int t = threadIdx.x;
    const int lane = t & 63, wv = t >> 6;
    const int kh = wv >> 2;
    const int wl = wv & 3;
    const int wm = (wl >> 1) * 32, wn = (wl & 1) * 32;
    const int tile_m = blockIdx.x * 64;

    f32x4 acc[2][2];
#pragma unroll
    for (int i = 0; i < 2; ++i)
#pragma unroll
        for (int j = 0; j < 2; ++j)
#pragma unroll
            for (int e = 0; e < 4; ++e) acc[i][j][e] = 0.f;

    const int ht = t & 255;
    int srow[2], soff[2], gr[2];
#pragma unroll
    for (int i = 0; i < 2; ++i) {
        int f = i * 256 + ht;
        srow[i] = f >> 3;
        soff[i] = ((f & 7) ^ (srow[i] & 7)) * 8;
        gr[i] = idxs[tile_m + srow[i]];
    }
    const int wvoff = wl * 1024;
    const int frow_a0 = wm + (lane & 15);
    const int frow_b0 = wn + (lane & 15);
    const int fk = (lane >> 4) * 16;
    const int kbase = kh * 2;

#define LSTAGE8(B, KT)                                                       \
    {                                                                        \
        _Pragma("unroll")                                                    \
        for (int i = 0; i < 2; ++i) {                                        \
            gload16(xf16 + (size_t)gr[i] * 256 + (kbase + (KT)) * 64         \
                        + soff[i],                                           \
                    (char*)As[B][kh] + wvoff + i * 4096);                    \
            gload16(WlP + (size_t)srow[i] * 256 + (kbase + (KT)) * 64        \
                        + soff[i],                                           \
                    (char*)Bs[B][kh] + wvoff + i * 4096);                    \
        }                                                                    \
    }

    int cur = 0;
    LSTAGE8(0, 0);
    __syncthreads();
#pragma unroll
    for (int kt = 0; kt < 2; ++kt) {
        if (kt + 1 < 2) LSTAGE8(cur ^ 1, kt + 1);
        const char* baseA = (const char*)As[cur][kh];
        const char* baseB = (const char*)Bs[cur][kh];
#pragma unroll
        for (int kk = 0; kk < 2; ++kk) {
            bf16x8 a[2], b[2];
#pragma unroll
            for (int mi = 0; mi < 2; ++mi) {
                int r = frow_a0 + mi * 16;
                a[mi] = *(const bf16x8*)(baseA + r * 128 +
                        ((kk * 64 + fk) ^ ((r & 7) << 4)));
            }
#pragma unroll
            for (int ni = 0; ni < 2; ++ni) {
                int r = frow_b0 + ni * 16;
                b[ni] = *(const bf16x8*)(baseB + r * 128 +
                        ((kk * 64 + fk) ^ ((r & 7) << 4)));
            }
#pragma unroll
            for (int mi = 0; mi < 2; ++mi)
#pragma unroll
                for (int ni = 0; ni < 2; ++ni)
                    acc[mi][ni] = __builtin_amdgcn_mfma_f32_16x16x32_bf16(
                        a[mi], b[ni], acc[mi][ni], 0, 0, 0);
        }
        __syncthreads();
        cur ^= 1;
    }
#undef LSTAGE8

    float* cb = (float*)&As[0][0][0];
    if (kh == 1) {
#pragma unroll
        for (int mi = 0; mi < 2; ++mi)
#pragma unroll
            for (int ni = 0; ni < 2; ++ni)
#pragma unroll
                for (int e = 0; e < 4; ++e)
                    cb[wl * 1024 + lane * 16 + (mi * 2 + ni) * 4 + e] =
                        acc[mi][ni][e];
    }
    __syncthreads();
    if (kh == 0) {
#pragma unroll
        for (int mi = 0; mi < 2; ++mi) {
#pragma unroll
            for (int ni = 0; ni < 2; ++ni) {
                int col = wn + ni * 16 + (lane & 15);
                if (col < 40) {
                    float bs = clP[col];
#pragma unroll
                    for (int e = 0; e < 4; ++e) {
                        int row = tile_m + wm + mi * 16 + ((lane >> 4) << 2) + e;
                        float c = acc[mi][ni][e] +
                            cb[wl * 1024 + lane * 16 + (mi * 2 + ni) * 4 + e];
                        out[(size_t)row * 40 + col] = c + bs;
                    }
                }
            }
        }
    }
}

// ---------------- attention + residual + LayerNorm (1 node/block) ----------
__global__ __launch_bounds__(256) void attn_ln_kernel(
    const u16* __restrict__ xh, const u16* __restrict__ x0,
    const float* __restrict__ asrc, const float* __restrict__ atgt,
    const int* __restrict__ nbr, const int* __restrict__ deg_,
    const float* __restrict__ ln_g, const float* __restrict__ ln_b,
    float* __restrict__ xln32, u16* __restrict__ xln16)
{
    __shared__ float att[CAP * 4];
    __shared__ int nb[CAP];
    __shared__ float red[8];
    const int i = blockIdx.x;
    const int t = threadIdx.x;
    const int wv = t >> 6, lane = t & 63;
    const int dg = deg_[i];

    for (int k = t; k < dg; k += 256) nb[k] = nbr[(size_t)i * CAP + k];
    __syncthreads();

    for (int idx = t; idx < dg * 4; idx += 256) {
        int k = idx >> 2, h = idx & 3;
        float e = asrc[nb[k] * 4 + h] + atgt[i * 4 + h];
        att[idx] = e > 0.f ? e : 0.2f * e;
    }
    __syncthreads();

    {
        const int h = wv;
        float m = -1e30f;
        for (int k = lane; k < dg; k += 64) m = fmaxf(m, att[k * 4 + h]);
#pragma unroll
        for (int off = 32; off > 0; off >>= 1) m = fmaxf(m, __shfl_xor(m, off));
        float s = 0.f;
        for (int k = lane; k < dg; k += 64) s += expf(att[k * 4 + h] - m);
#pragma unroll
        for (int off = 32; off > 0; off >>= 1) s += __shfl_xor(s, off);
        float inv = 1.0f / s;
        for (int k = lane; k < dg; k += 64)
            att[k * 4 + h] = expf(att[k * 4 + h] - m) * inv;
    }

    const int h = wv;
    float acc = 0.f;
    int k = 0;
    for (; k + 4 <= dg; k += 4) {
        float a0 = att[(k + 0) * 4 + h], v0 = bf2f(xh[(size_t)nb[k + 0] * 256 + t]);
        float a1 = att[(k + 1) * 4 + h], v1 = bf2f(xh[(size_t)nb[k + 1] * 256 + t]);
        float a2 = att[(k + 2) * 4 + h], v2 = bf2f(xh[(size_t)nb[k + 2] * 256 + t]);
        float a3 = att[(k + 3) * 4 + h], v3 = bf2f(xh[(size_t)nb[k + 3] * 256 + t]);
        acc = fmaf(a0, v0, acc); acc = fmaf(a1, v1, acc);
        acc = fmaf(a2, v2, acc); acc = fmaf(a3, v3, acc);
    }
    for (; k < dg; ++k)
        acc = fmaf(att[k * 4 + h], bf2f(xh[(size_t)nb[k] * 256 + t]), acc);

    float v = bf2f(x0[(size_t)i * 256 + t]) + acc;
    float s = v, q = v * v;
#pragma unroll
    for (int off = 32; off > 0; off >>= 1) {
        s += __shfl_xor(s, off);
        q += __shfl_xor(q, off);
    }
    if (lane == 0) { red[wv] = s; red[4 + wv] = q; }
    __syncthreads();
    float S = red[0] + red[1] + red[2] + red[3];
    float Q = red[4] + red[5] + red[6] + red[7];
    float mu = S * (1.0f / 256.0f);
    float var = Q * (1.0f / 256.0f) - mu * mu;
    float y = (v - mu) * rsqrtf(var + 1e-5f) * ln_g[t] + ln_b[t];
    xln32[(size_t)i * 256 + t] = y;
    xln16[(size_t)i * 256 + t] = f2bf(y);
}

// ---------------------------------------------------------------------------
extern "C" void kernel_launch(void* const* d_in, const int* in_sizes, int n_in,
                              void* d_out, int out_size, void* d_ws, size_t ws_size,
                              hipStream_t stream)
{
    const float* nf      = (const float*)d_in[0];
    const float* pre_g1  = (const float*)d_in[1];
    const float* pre_b1  = (const float*)d_in[2];
    const float* pre_W1  = (const float*)d_in[3];
    const float* pre_c1  = (const float*)d_in[4];
    const float* pre_g2  = (const float*)d_in[5];
    const float* pre_b2  = (const float*)d_in[6];
    const float* pre_W2  = (const float*)d_in[7];
    const float* pre_c2  = (const float*)d_in[8];
    const float* Wp      = (const float*)d_in[9];
    const float* Wa      = (const float*)d_in[10];
    const float* ln_g    = (const float*)d_in[11];
    const float* ln_b    = (const float*)d_in[12];
    const float* post_g1 = (const float*)d_in[13];
    const float* post_b1 = (const float*)d_in[14];
    const float* post_W1 = (const float*)d_in[15];
    const float* post_c1 = (const float*)d_in[16];
    const float* post_g2 = (const float*)d_in[17];
    const float* post_b2 = (const float*)d_in[18];
    const float* post_W2 = (const float*)d_in[19];
    const float* post_c2 = (const float*)d_in[20];
    const float* Wl      = (const float*)d_in[21];
    const float* cl      = (const float*)d_in[22];
    const unsigned char* adj = (const unsigned char*)d_in[23];
    const int* idxs      = (const int*)d_in[24];
    float* out = (float*)d_out;

    size_t off = 0;
    char* base = (char*)d_ws;
    auto carve = [&](size_t bytes) {
        void* p = base + off;
        off += (bytes + 255) & ~(size_t)255;
        return p;
    };
    u16*   Y16   = (u16*)  carve((size_t)4096 * 1024 * 2);
    u16*   NF16  = (u16*)  carve((size_t)4096 * 512 * 2);
    u16*   X016  = (u16*)  carve((size_t)4096 * 256 * 2);
    u16*   XH16  = (u16*)  carve((size_t)4096 * 256 * 2);
    float* XLN32 = (float*)carve((size_t)4096 * 256 * 4);
    u16*   XLN16 = (u16*)  carve((size_t)4096 * 256 * 2);
    u16*   XF16  = (u16*)  carve((size_t)4096 * 256 * 2);
    u16*   W1_16 = (u16*)  carve((size_t)1024 * 512 * 2);
    u16*   W2_16 = (u16*)  carve((size_t)256 * 1024 * 2);
    u16*   Wp16  = (u16*)  carve((size_t)256 * 256 * 2);
    u16*   W3_16 = (u16*)  carve((size_t)1024 * 256 * 2);
    u16*   W4_16 = (u16*)  carve((size_t)256 * 1024 * 2);
    u16*   WlP16 = (u16*)  carve((size_t)64 * 256 * 2);
    float* B1    = (float*)carve(1024 * 4);
    float* B2    = (float*)carve(256 * 4);
    float* B3    = (float*)carve(1024 * 4);
    float* B4    = (float*)carve(256 * 4);
    float* CLP   = (float*)carve(64 * 4);
    int*   NBR   = (int*)  carve((size_t)4096 * CAP * 4);
    int*   DEG   = (int*)  carve((size_t)4096 * 4);
    float* ASRC  = (float*)carve((size_t)4096 * 4 * 4);
    float* ATGT  = (float*)carve((size_t)4096 * 4 * 4);
    float* PART  = (float*)carve((size_t)512 * 512 * 2 * 4);
    float* SCL1  = (float*)carve(512 * 4);
    float* SHF1  = (float*)carve(512 * 4);
    float* SCL2  = (float*)carve(1024 * 4);
    float* SHF2  = (float*)carve(1024 * 4);
    float* SCL3  = (float*)carve(256 * 4);
    float* SHF3  = (float*)carve(256 * 4);
    float* SCL4  = (float*)carve(1024 * 4);
    float* SHF4  = (float*)carve(1024 * 4);
    (void)ws_size; (void)n_in; (void)in_sizes; (void)out_size;

    // 1) prep: nbr lists (512 blocks x 8 rows, atomic compaction)
    //    + nf stats + Wp/Wl folds
    prep_kernel<<<512 + 128 + 320, 256, 0, stream>>>(
        adj, NBR, DEG, nf, PART, NF16, Wp, Wl, cl, Wp16, WlP16, CLP);

    // 2) stage 1: BN1 final + fold + GEMM1 -> Y16 + PART(BN2 stats)
    colstats_final<<<512 / 16, 256, 0, stream>>>(PART, pre_g1, pre_b1, SCL1, SHF1, 256, 512);
    foldw_kernel<<<1024, 256, 0, stream>>>(pre_W1, SCL1, SHF1, pre_c1, W1_16, B1, 512, 1024);
    mfma_gemm<true, true, true><<<dim3(16, 64), 256, 0, stream>>>(
        NF16, W1_16, B1, Y16, PART, 4096, 1024, 512);

    // 3) stage 2: BN2 final + fold + GEMM2 (split-K 8w) -> X016
    colstats_final<<<1024 / 16, 256, 0, stream>>>(PART, pre_g2, pre_b2, SCL2, SHF2, 64, 1024);
    foldw_kernel<<<256, 256, 0, stream>>>(pre_W2, SCL2, SHF2, pre_c2, W2_16, B2, 1024, 256);
    mfma_gemm8<true, true, false><<<dim3(4, 64), 512, 0, stream>>>(
        Y16, W2_16, B2, X016, nullptr, nullptr, nullptr, 4096, 256, 1024);

    // 4) GEMM3 (split-K 8w) -> XH16 + fused a_src/a_tgt
    mfma_gemm8<false, true, true><<<dim3(4, 64), 512, 0, stream>>>(
        X016, Wp16, nullptr, XH16, Wa, ASRC, ATGT, 4096, 256, 256);

    // 5) attention + residual + LN (4096 blocks)
    attn_ln_kernel<<<4096, 256, 0, stream>>>(XH16, X016, ASRC, ATGT, NBR, DEG,
                                             ln_g, ln_b, XLN32, XLN16);

    // 6) stage 4: BN3 stats + final + fold + GEMM4 -> Y16 + PART(BN4 stats)
    xln_stats<<<128, 256, 0, stream>>>(XLN32, PART);
    colstats_final<<<256 / 16, 256, 0, stream>>>(PART, post_g1, post_b1, SCL3, SHF3, 512, 256);
    foldw_kernel<<<1024, 256, 0, stream>>>(post_W1, SCL3, SHF3, post_c1, W3_16, B3, 256, 1024);
    mfma_gemm<true, true, true><<<dim3(16, 64), 256, 0, stream>>>(
        XLN16, W3_16, B3, Y16, PART, 4096, 1024, 256);

    // 7) stage 5: BN4 final + fold + GEMM5 (split-K 8w) -> XF16
    colstats_final<<<1024 / 16, 256, 0, stream>>>(PART, post_g2, post_b2, SCL4, SHF4, 64, 1024);
    foldw_kernel<<<256, 256, 0, stream>>>(post_W2, SCL4, SHF4, post_c2, W4_16, B4, 1024, 256);
    mfma_gemm8<true, true, false><<<dim3(4, 64), 512, 0, stream>>>(
        Y16, W4_16, B4, XF16, nullptr, nullptr, nullptr, 4096, 256, 1024);

    // 8) gathered logits (split-K 8w)
    logits_mfma<<<128, 512, 0, stream>>>(XF16, idxs, WlP16, CLP, out);
}